// Round 1
// baseline (1751.534 us; speedup 1.0000x reference)
//
#include <hip/hip_runtime.h>
#include <cmath>

#define LDIM 4096
#define CDIM 768
#define BDIM 2
#define NST 4
#define RNK 48
#define DBLW 56   // RNK + 2*NST
#define CH 64     // scan chunks per sequence
#define LC 64     // chunk length (CH*LC == LDIM)

__device__ __forceinline__ float sigmoidf_(float x) { return 1.f / (1.f + __expf(-x)); }

// ---------------- LayerNorm over C; x and xn both in (B, C, L) layout ----------------
__global__ __launch_bounds__(256) void ln_kernel(const float* __restrict__ x,
                                                 const float* __restrict__ g,
                                                 const float* __restrict__ bb,
                                                 float* __restrict__ xn)
{
    int idx = blockIdx.x * 256 + threadIdx.x;  // b*L + l
    int l = idx & (LDIM - 1);
    int b = idx >> 12;
    const float* xp = x + (size_t)b * CDIM * LDIM + l;
    float s0 = 0, s1 = 0, s2 = 0, s3 = 0, q0 = 0, q1 = 0, q2 = 0, q3 = 0;
    for (int c = 0; c < CDIM; c += 4) {
        float v0 = xp[(c + 0) * LDIM];
        float v1 = xp[(c + 1) * LDIM];
        float v2 = xp[(c + 2) * LDIM];
        float v3 = xp[(c + 3) * LDIM];
        s0 += v0; s1 += v1; s2 += v2; s3 += v3;
        q0 += v0 * v0; q1 += v1 * v1; q2 += v2 * v2; q3 += v3 * v3;
    }
    float m = (s0 + s1 + s2 + s3) * (1.f / CDIM);
    float var = (q0 + q1 + q2 + q3) * (1.f / CDIM) - m * m;
    float rs = rsqrtf(var + 1e-5f);
    float* op = xn + (size_t)b * CDIM * LDIM + l;
    for (int c = 0; c < CDIM; ++c) {
        float v = xp[c * LDIM];
        op[c * LDIM] = (v - m) * rs * g[c] + bb[c];
    }
}

// ---------------- Generic fp32 tiled GEMM: C(MxN) = A(MxK) * B(KxN) ----------------
// amode 0: A row-major with stride lda.
// amode 1: A is (B,C,L)-layout transposed activations: elem (r,k) at (r>>12)*C*L + k*L + (r&4095)
// epi 0: none; epi 1: softplus(v + bias[col]); epi 2: v + resid[(r>>12)*C*L + col*L + (r&4095)]
#define TS 64
#define KT 16
__global__ __launch_bounds__(256) void gemm_tiled(
    const float* __restrict__ A, int lda, int amode,
    const float* __restrict__ B, int ldb,
    float* __restrict__ C, int ldc,
    int M, int N, int K,
    int epi, const float* __restrict__ bias, const float* __restrict__ resid)
{
    __shared__ float As[KT][TS + 4];
    __shared__ float Bs[KT][TS + 4];
    const int tid = threadIdx.x;
    const int tx = tid & 15, ty = tid >> 4;
    const int row0 = blockIdx.y * TS, col0 = blockIdx.x * TS;
    float acc[4][4] = {};

    for (int k0 = 0; k0 < K; k0 += KT) {
        if (amode == 1) {
            // fully coalesced: contiguous in m
            for (int i = tid; i < KT * TS; i += 256) {
                int kk = i >> 6, mm = i & 63;
                int r = row0 + mm, k = k0 + kk;
                As[kk][mm] = A[((size_t)(r >> 12) * CDIM + k) * LDIM + (r & (LDIM - 1))];
            }
        } else {
            for (int i = tid; i < KT * TS; i += 256) {
                int kk = i & 15, mm = i >> 4;
                int r = row0 + mm, k = k0 + kk;
                float v = 0.f;
                if (r < M && k < K) v = A[(size_t)r * lda + k];
                As[kk][mm] = v;
            }
        }
        for (int i = tid; i < KT * TS; i += 256) {
            int kk = i >> 6, nn = i & 63;
            int k = k0 + kk, c = col0 + nn;
            float v = 0.f;
            if (k < K && c < N) v = B[(size_t)k * ldb + c];
            Bs[kk][nn] = v;
        }
        __syncthreads();
#pragma unroll
        for (int kk = 0; kk < KT; ++kk) {
            float a[4], b[4];
#pragma unroll
            for (int i = 0; i < 4; i++) a[i] = As[kk][ty * 4 + i];
#pragma unroll
            for (int j = 0; j < 4; j++) b[j] = Bs[kk][tx * 4 + j];
#pragma unroll
            for (int i = 0; i < 4; i++)
#pragma unroll
                for (int j = 0; j < 4; j++) acc[i][j] += a[i] * b[j];
        }
        __syncthreads();
    }

#pragma unroll
    for (int i = 0; i < 4; i++) {
        int r = row0 + ty * 4 + i;
        if (r >= M) continue;
#pragma unroll
        for (int j = 0; j < 4; j++) {
            int c = col0 + tx * 4 + j;
            if (c >= N) continue;
            float v = acc[i][j];
            if (epi == 1) {
                v += bias[c];
                v = (v > 20.f) ? v : log1pf(__expf(v));
            } else if (epi == 2) {
                v += resid[((size_t)(r >> 12) * CDIM + c) * LDIM + (r & (LDIM - 1))];
            }
            C[(size_t)r * ldc + c] = v;
        }
    }
}

// ---------------- depthwise causal conv (K=4) + SiLU: uz[:, :768] -> u ----------------
__global__ __launch_bounds__(256) void conv_silu_kernel(const float* __restrict__ uz,
                                                        const float* __restrict__ w,
                                                        const float* __restrict__ bc,
                                                        float* __restrict__ u)
{
    int idx = blockIdx.x * 256 + threadIdx.x;  // (b*L + l)*D + d
    int d = idx % CDIM;
    int bl = idx / CDIM;
    int l = bl & (LDIM - 1);
    float acc = bc[d];
    const float* wp = w + d * 4;
#pragma unroll
    for (int k = 0; k < 4; k++) {
        int ls = l - 3 + k;
        if (ls >= 0) acc += uz[(size_t)(bl - 3 + k) * (2 * CDIM) + d] * wp[k];
    }
    u[idx] = acc * sigmoidf_(acc);
}

// ---------------- chunked selective scan ----------------
// idx = ((s*2 + b)*CH + c)*CDIM + d
__global__ __launch_bounds__(256) void scan_phaseA(
    const float* __restrict__ u0, const float* __restrict__ dt0, const float* __restrict__ dbl0, const float* __restrict__ Alog0,
    const float* __restrict__ u1, const float* __restrict__ dt1, const float* __restrict__ dbl1, const float* __restrict__ Alog1,
    float* __restrict__ agg)
{
    int idx = blockIdx.x * 256 + threadIdx.x;
    int d = idx % CDIM;
    int t1 = idx / CDIM;
    int c = t1 % CH;
    int t2 = t1 / CH;
    int b = t2 & 1;
    int s = t2 >> 1;
    const float* u = s ? u1 : u0;
    const float* dt = s ? dt1 : dt0;
    const float* dbl = s ? dbl1 : dbl0;
    const float* Alog = s ? Alog1 : Alog0;
    float A[4];
#pragma unroll
    for (int n = 0; n < 4; n++) A[n] = -__expf(Alog[d * 4 + n]);
    float h[4] = {0, 0, 0, 0}, aa[4] = {1, 1, 1, 1};
    int rowb = b * LDIM + c * LC;
    for (int t = 0; t < LC; t++) {
        int row = rowb + t;
        float dtv = dt[(size_t)row * CDIM + d];
        float uv = u[(size_t)row * CDIM + d];
        float du = dtv * uv;
        const float* bm = dbl + (size_t)row * DBLW + RNK;
#pragma unroll
        for (int n = 0; n < 4; n++) {
            float dA = __expf(dtv * A[n]);
            h[n] = dA * h[n] + du * bm[n];
            aa[n] *= dA;
        }
    }
    float* o = agg + (size_t)idx * 8;
#pragma unroll
    for (int n = 0; n < 4; n++) { o[n] = aa[n]; o[4 + n] = h[n]; }
}

__global__ __launch_bounds__(256) void scan_phaseB(const float* __restrict__ agg,
                                                   float* __restrict__ hinit)
{
    int idx = blockIdx.x * 256 + threadIdx.x;  // (s*2+b)*CDIM + d ordering below
    int d = idx % CDIM;
    int sb = idx / CDIM;
    float st[4] = {0, 0, 0, 0};
    for (int c = 0; c < CH; c++) {
        size_t base = ((size_t)sb * CH + c) * CDIM + d;
        const float* a = agg + base * 8;
        float* hi = hinit + base * 4;
#pragma unroll
        for (int n = 0; n < 4; n++) hi[n] = st[n];
#pragma unroll
        for (int n = 0; n < 4; n++) st[n] = a[n] * st[n] + a[4 + n];
    }
}

__global__ __launch_bounds__(256) void scan_phaseC(
    float* __restrict__ u0, const float* __restrict__ dt0, const float* __restrict__ dbl0,
    const float* __restrict__ Alog0, const float* __restrict__ Dsk0, const float* __restrict__ uz0,
    float* __restrict__ u1, const float* __restrict__ dt1, const float* __restrict__ dbl1,
    const float* __restrict__ Alog1, const float* __restrict__ Dsk1, const float* __restrict__ uz1,
    const float* __restrict__ hinit)
{
    int idx = blockIdx.x * 256 + threadIdx.x;
    int d = idx % CDIM;
    int t1 = idx / CDIM;
    int c = t1 % CH;
    int t2 = t1 / CH;
    int b = t2 & 1;
    int s = t2 >> 1;
    float* u = s ? u1 : u0;
    const float* dt = s ? dt1 : dt0;
    const float* dbl = s ? dbl1 : dbl0;
    const float* dblO = s ? dbl0 : dbl1;  // cross: other stream's C projection
    const float* Alog = s ? Alog1 : Alog0;
    const float* Dsk = s ? Dsk1 : Dsk0;
    const float* uz = s ? uz1 : uz0;
    float A[4];
#pragma unroll
    for (int n = 0; n < 4; n++) A[n] = -__expf(Alog[d * 4 + n]);
    float Dv = Dsk[d];
    float h[4];
    const float* hi = hinit + (size_t)idx * 4;
#pragma unroll
    for (int n = 0; n < 4; n++) h[n] = hi[n];
    int rowb = b * LDIM + c * LC;
    for (int t = 0; t < LC; t++) {
        int row = rowb + t;
        float dtv = dt[(size_t)row * CDIM + d];
        float uv = u[(size_t)row * CDIM + d];
        float du = dtv * uv;
        const float* bm = dbl + (size_t)row * DBLW + RNK;
        const float* cm = dblO + (size_t)row * DBLW + RNK + NST;
        float y = 0.f;
#pragma unroll
        for (int n = 0; n < 4; n++) {
            float dA = __expf(dtv * A[n]);
            h[n] = dA * h[n] + du * bm[n];
            y += h[n] * cm[n];
        }
        y += uv * Dv;
        float zv = uz[(size_t)row * (2 * CDIM) + CDIM + d];
        u[(size_t)row * CDIM + d] = y * (zv * sigmoidf_(zv));  // fused gating, in-place
    }
}

extern "C" void kernel_launch(void* const* d_in, const int* in_sizes, int n_in,
                              void* d_out, int out_size, void* d_ws, size_t ws_size,
                              hipStream_t stream)
{
    const float* x[2] = {(const float*)d_in[0], (const float*)d_in[1]};
    const float *ln_g[2], *ln_b[2], *Win[2], *Wconv[2], *bconv[2], *Wxp[2],
        *Wdt[2], *bdt[2], *Alog[2], *Dskip[2], *Wout[2];
    for (int s = 0; s < 2; s++) {
        int base = 2 + s * 11;
        ln_g[s] = (const float*)d_in[base + 0];
        ln_b[s] = (const float*)d_in[base + 1];
        Win[s] = (const float*)d_in[base + 2];
        Wconv[s] = (const float*)d_in[base + 3];
        bconv[s] = (const float*)d_in[base + 4];
        Wxp[s] = (const float*)d_in[base + 5];
        Wdt[s] = (const float*)d_in[base + 6];
        bdt[s] = (const float*)d_in[base + 7];
        Alog[s] = (const float*)d_in[base + 8];
        Dskip[s] = (const float*)d_in[base + 9];
        Wout[s] = (const float*)d_in[base + 10];
    }

    float* ws = (float*)d_ws;
    const size_t SZ = (size_t)BDIM * LDIM * CDIM;  // 6291456
    float* xn[2] = {ws, ws + SZ};                  // later reused for dt
    float* uz[2] = {ws + 2 * SZ, ws + 4 * SZ};     // each 2*SZ
    float* u[2] = {ws + 6 * SZ, ws + 7 * SZ};
    const size_t SZ_DBL = (size_t)BDIM * LDIM * DBLW;  // 458752
    float* dbl[2] = {ws + 8 * SZ, ws + 8 * SZ + SZ_DBL};
    float* agg = ws + 8 * SZ + 2 * SZ_DBL;                // 2*2*CH*CDIM*8 = 1572864
    float* hinit = agg + (size_t)2 * BDIM * CH * CDIM * 8;  // 786432

    const int M = BDIM * LDIM;  // 8192
    dim3 blk(256);

    for (int s = 0; s < 2; s++) {
        // 1. LN (transposed layout in/out)
        ln_kernel<<<dim3(M / 256), blk, 0, stream>>>(x[s], ln_g[s], ln_b[s], xn[s]);
        // 2. in_proj: xn^T(8192x768) @ Win(768x1536) -> uz
        gemm_tiled<<<dim3(1536 / TS, M / TS), blk, 0, stream>>>(
            xn[s], 0, 1, Win[s], 2 * CDIM, uz[s], 2 * CDIM, M, 2 * CDIM, CDIM, 0, nullptr, nullptr);
        // 3. depthwise conv + SiLU
        conv_silu_kernel<<<dim3((M * CDIM) / 256), blk, 0, stream>>>(uz[s], Wconv[s], bconv[s], u[s]);
        // 4. x_proj: u @ Wxp(768x56) -> dbl
        gemm_tiled<<<dim3(1, M / TS), blk, 0, stream>>>(
            u[s], CDIM, 0, Wxp[s], DBLW, dbl[s], DBLW, M, DBLW, CDIM, 0, nullptr, nullptr);
        // 5. dt = softplus(dtr @ Wdt + bdt) -> reuse xn buffer
        gemm_tiled<<<dim3(CDIM / TS, M / TS), blk, 0, stream>>>(
            dbl[s], DBLW, 0, Wdt[s], CDIM, xn[s], CDIM, M, CDIM, RNK, 1, bdt[s], nullptr);
    }

    // 6. cross selective scan (chunked, 3 phases), gating fused into phase C
    scan_phaseA<<<dim3((2 * BDIM * CH * CDIM) / 256), blk, 0, stream>>>(
        u[0], xn[0], dbl[0], Alog[0], u[1], xn[1], dbl[1], Alog[1], agg);
    scan_phaseB<<<dim3((2 * BDIM * CDIM) / 256), blk, 0, stream>>>(agg, hinit);
    scan_phaseC<<<dim3((2 * BDIM * CH * CDIM) / 256), blk, 0, stream>>>(
        u[0], xn[0], dbl[0], Alog[0], Dskip[0], uz[0],
        u[1], xn[1], dbl[1], Alog[1], Dskip[1], uz[1], hinit);

    // 7. out_proj + residual (residual reads original x in native (B,C,L) layout)
    float* out = (float*)d_out;
    for (int s = 0; s < 2; s++) {
        gemm_tiled<<<dim3(CDIM / TS, M / TS), blk, 0, stream>>>(
            u[s], CDIM, 0, Wout[s], CDIM, out + s * SZ, CDIM, M, CDIM, CDIM, 2, nullptr, x[s]);
    }
}

// Round 2
// 885.609 us; speedup vs baseline: 1.9778x; 1.9778x over previous
//
#include <hip/hip_runtime.h>
#include <cmath>

#define LDIM 4096
#define CDIM 768
#define BDIM 2
#define NST 4
#define RNK 48
#define DBLW 56   // RNK + 2*NST
#define CH 64     // scan chunks per sequence
#define LC 64     // chunk length (CH*LC == LDIM)

typedef short bf16x8 __attribute__((ext_vector_type(8)));
typedef float f32x4 __attribute__((ext_vector_type(4)));

__device__ __forceinline__ float sigmoidf_(float x) { return 1.f / (1.f + __expf(-x)); }

__device__ __forceinline__ unsigned short f2bf(float f) {
    unsigned int u = __float_as_uint(f);
    u += 0x7fffu + ((u >> 16) & 1u);
    return (unsigned short)(u >> 16);
}

__device__ __forceinline__ void llds16(const unsigned short* g, unsigned short* l) {
    __builtin_amdgcn_global_load_lds(
        (const __attribute__((address_space(1))) unsigned int*)g,
        (__attribute__((address_space(3))) unsigned int*)l, 16, 0, 0);
}

// ---------- LN stats: mean/rstd per (s,b,l) ----------
__global__ __launch_bounds__(256) void stats_kernel(const float* __restrict__ x0,
                                                    const float* __restrict__ x1,
                                                    float* __restrict__ stats)
{
    int idx = blockIdx.x * 256 + threadIdx.x;  // s*8192 + b*4096 + l
    int s = idx >> 13;
    int bl = idx & 8191;
    int b = bl >> 12, l = bl & (LDIM - 1);
    const float* x = s ? x1 : x0;
    const float* xp = x + (size_t)b * CDIM * LDIM + l;
    float s0 = 0, s1 = 0, q0 = 0, q1 = 0;
    for (int c = 0; c < CDIM; c += 2) {
        float v0 = xp[(size_t)(c + 0) * LDIM];
        float v1 = xp[(size_t)(c + 1) * LDIM];
        s0 += v0; s1 += v1; q0 += v0 * v0; q1 += v1 * v1;
    }
    float m = (s0 + s1) * (1.f / CDIM);
    float var = (q0 + q1) * (1.f / CDIM) - m * m;
    stats[idx * 2] = m;
    stats[idx * 2 + 1] = rsqrtf(var + 1e-5f);
}

// ---------- transpose + LN: x (B,C,L) -> xn bf16 (B*L, C) and raw x -> d_out (residual pre-store) ----------
__global__ __launch_bounds__(256) void transpose_ln_kernel(
    const float* __restrict__ x0, const float* __restrict__ x1,
    const float* __restrict__ g0, const float* __restrict__ bb0,
    const float* __restrict__ g1, const float* __restrict__ bb1,
    const float* __restrict__ stats,
    unsigned short* __restrict__ xnb0, unsigned short* __restrict__ xnb1,
    float* __restrict__ out)
{
    __shared__ float tile[64][65];
    int t = threadIdx.x;
    int c0 = blockIdx.x * 64, l0 = blockIdx.y * 64;
    int z = blockIdx.z;
    int s = z >> 1, b = z & 1;
    const float* x = s ? x1 : x0;
    const float* g = s ? g1 : g0;
    const float* bb = s ? bb1 : bb0;
    unsigned short* xnb = s ? xnb1 : xnb0;
    int tl = t & 63, tg = t >> 6;
#pragma unroll
    for (int i = 0; i < 16; i++) {
        int cl = tg * 16 + i;
        tile[cl][tl] = x[((size_t)(b * CDIM + c0 + cl)) * LDIM + l0 + tl];
    }
    __syncthreads();
    const size_t SZ = (size_t)BDIM * LDIM * CDIM;
#pragma unroll
    for (int i = 0; i < 16; i++) {
        int ll = tg * 16 + i;
        int l = l0 + ll, c = c0 + tl;
        float v = tile[tl][ll];
        int sidx = s * 8192 + b * LDIM + l;
        float m = stats[sidx * 2], rs = stats[sidx * 2 + 1];
        size_t o = ((size_t)(b * LDIM + l)) * CDIM + c;
        out[(size_t)s * SZ + o] = v;  // residual pre-store (raw x, transposed)
        xnb[o] = f2bf((v - m) * rs * g[c] + bb[c]);
    }
}

// ---------- weight transpose/convert: W (K,N) fp32 -> Wt (N,K) bf16 ----------
__global__ __launch_bounds__(256) void wt_transpose(const float* __restrict__ W,
                                                    unsigned short* __restrict__ Wt,
                                                    int K, int N)
{
    __shared__ float tile[64][65];
    int t = threadIdx.x;
    int n0 = blockIdx.x * 64, k0 = blockIdx.y * 64;
    int tn = t & 63, tg = t >> 6;
#pragma unroll
    for (int i = 0; i < 16; i++) {
        int kl = tg * 16 + i;
        tile[kl][tn] = W[(size_t)(k0 + kl) * N + n0 + tn];
    }
    __syncthreads();
#pragma unroll
    for (int i = 0; i < 16; i++) {
        int nl = tg * 16 + i;
        int k = k0 + tn, n = n0 + nl;
        Wt[(size_t)n * K + k] = f2bf(tile[tn][nl]);
    }
}

// ---------- bf16 MFMA GEMM: C(MxN) fp32 = A(M,K)bf16 @ Bt(N,K)bf16^T ----------
// epi 0: store; epi 1: C += acc (residual pre-stored in C)
__global__ __launch_bounds__(256) void gemm_mfma(
    const unsigned short* __restrict__ A, const unsigned short* __restrict__ Bt,
    float* __restrict__ C, int ldc, int K, int epi)
{
    __shared__ unsigned short As[128 * 32];
    __shared__ unsigned short Bs[128 * 32];
    const int tid = threadIdx.x;
    const int wave = tid >> 6, lane = tid & 63;
    const int row0 = blockIdx.y * 128, col0 = blockIdx.x * 128;
    const int wm = (wave >> 1) * 64, wn = (wave & 1) * 64;
    f32x4 acc[4][4] = {};
    const int lr = lane >> 2;       // staging: row within 16-row group
    const int lk = (lane & 3) * 8;  // staging: k offset (8 bf16 = 16B)
    const int fr = lane & 15, fk = (lane >> 4) * 8;  // fragment indices

    for (int k0 = 0; k0 < K; k0 += 32) {
#pragma unroll
        for (int h = 0; h < 2; h++) {
            int rb = wave * 32 + h * 16;
            const unsigned short* ga = A + (size_t)(row0 + rb + lr) * K + k0 + lk;
            const unsigned short* gb = Bt + (size_t)(col0 + rb + lr) * K + k0 + lk;
            llds16(ga, &As[rb * 32]);
            llds16(gb, &Bs[rb * 32]);
        }
        __syncthreads();
        bf16x8 af[4], bfr[4];
#pragma unroll
        for (int i = 0; i < 4; i++)
            af[i] = *(const bf16x8*)&As[(wm + i * 16 + fr) * 32 + fk];
#pragma unroll
        for (int j = 0; j < 4; j++)
            bfr[j] = *(const bf16x8*)&Bs[(wn + j * 16 + fr) * 32 + fk];
#pragma unroll
        for (int i = 0; i < 4; i++)
#pragma unroll
            for (int j = 0; j < 4; j++)
                acc[i][j] = __builtin_amdgcn_mfma_f32_16x16x32_bf16(af[i], bfr[j], acc[i][j], 0, 0, 0);
        __syncthreads();
    }

    const int cr = (lane >> 4) * 4, cc = lane & 15;
#pragma unroll
    for (int i = 0; i < 4; i++)
#pragma unroll
        for (int j = 0; j < 4; j++) {
            int col = col0 + wn + j * 16 + cc;
#pragma unroll
            for (int r = 0; r < 4; r++) {
                int row = row0 + wm + i * 16 + cr + r;
                size_t o = (size_t)row * ldc + col;
                float v = acc[i][j][r];
                if (epi) v += C[o];
                C[o] = v;
            }
        }
}

// ---------- fp32 tiled GEMM (small GEMMs: x_proj, dt) ----------
#define TS 64
#define KT 16
__global__ __launch_bounds__(256) void gemm_tiled(
    const float* __restrict__ A, int lda,
    const float* __restrict__ B, int ldb,
    float* __restrict__ C, int ldc,
    int M, int N, int K,
    int epi, const float* __restrict__ bias)
{
    __shared__ float As[KT][TS + 4];
    __shared__ float Bs[KT][TS + 4];
    const int tid = threadIdx.x;
    const int tx = tid & 15, ty = tid >> 4;
    const int row0 = blockIdx.y * TS, col0 = blockIdx.x * TS;
    float acc[4][4] = {};

    for (int k0 = 0; k0 < K; k0 += KT) {
        for (int i = tid; i < KT * TS; i += 256) {
            int kk = i & 15, mm = i >> 4;
            int r = row0 + mm, k = k0 + kk;
            float v = 0.f;
            if (r < M && k < K) v = A[(size_t)r * lda + k];
            As[kk][mm] = v;
        }
        for (int i = tid; i < KT * TS; i += 256) {
            int kk = i >> 6, nn = i & 63;
            int k = k0 + kk, c = col0 + nn;
            float v = 0.f;
            if (k < K && c < N) v = B[(size_t)k * ldb + c];
            Bs[kk][nn] = v;
        }
        __syncthreads();
#pragma unroll
        for (int kk = 0; kk < KT; ++kk) {
            float a[4], b[4];
#pragma unroll
            for (int i = 0; i < 4; i++) a[i] = As[kk][ty * 4 + i];
#pragma unroll
            for (int j = 0; j < 4; j++) b[j] = Bs[kk][tx * 4 + j];
#pragma unroll
            for (int i = 0; i < 4; i++)
#pragma unroll
                for (int j = 0; j < 4; j++) acc[i][j] += a[i] * b[j];
        }
        __syncthreads();
    }

#pragma unroll
    for (int i = 0; i < 4; i++) {
        int r = row0 + ty * 4 + i;
        if (r >= M) continue;
#pragma unroll
        for (int j = 0; j < 4; j++) {
            int c = col0 + tx * 4 + j;
            if (c >= N) continue;
            float v = acc[i][j];
            if (epi == 1) {
                v += bias[c];
                v = (v > 20.f) ? v : log1pf(__expf(v));
            }
            C[(size_t)r * ldc + c] = v;
        }
    }
}

// ---------- depthwise causal conv (K=4) + SiLU ----------
__global__ __launch_bounds__(256) void conv_silu_kernel(const float* __restrict__ uz,
                                                        const float* __restrict__ w,
                                                        const float* __restrict__ bc,
                                                        float* __restrict__ u)
{
    int idx = blockIdx.x * 256 + threadIdx.x;  // (b*L + l)*D + d
    int d = idx % CDIM;
    int bl = idx / CDIM;
    int l = bl & (LDIM - 1);
    float acc = bc[d];
    const float* wp = w + d * 4;
#pragma unroll
    for (int k = 0; k < 4; k++) {
        int ls = l - 3 + k;
        if (ls >= 0) acc += uz[(size_t)(bl - 3 + k) * (2 * CDIM) + d] * wp[k];
    }
    u[idx] = acc * sigmoidf_(acc);
}

// ---------- chunked selective scan; dt lives in uz[:, :768] (stride 1536) ----------
__global__ __launch_bounds__(256) void scan_phaseA(
    const float* __restrict__ u0, const float* __restrict__ uz0, const float* __restrict__ dbl0, const float* __restrict__ Alog0,
    const float* __restrict__ u1, const float* __restrict__ uz1, const float* __restrict__ dbl1, const float* __restrict__ Alog1,
    float* __restrict__ agg)
{
    int idx = blockIdx.x * 256 + threadIdx.x;
    int d = idx % CDIM;
    int t1 = idx / CDIM;
    int c = t1 % CH;
    int t2 = t1 / CH;
    int b = t2 & 1;
    int s = t2 >> 1;
    const float* u = s ? u1 : u0;
    const float* dt = s ? uz1 : uz0;
    const float* dbl = s ? dbl1 : dbl0;
    const float* Alog = s ? Alog1 : Alog0;
    float A[4];
#pragma unroll
    for (int n = 0; n < 4; n++) A[n] = -__expf(Alog[d * 4 + n]);
    float h[4] = {0, 0, 0, 0}, aa[4] = {1, 1, 1, 1};
    int rowb = b * LDIM + c * LC;
    for (int t = 0; t < LC; t++) {
        int row = rowb + t;
        float dtv = dt[(size_t)row * (2 * CDIM) + d];
        float uv = u[(size_t)row * CDIM + d];
        float du = dtv * uv;
        const float* bm = dbl + (size_t)row * DBLW + RNK;
#pragma unroll
        for (int n = 0; n < 4; n++) {
            float dA = __expf(dtv * A[n]);
            h[n] = dA * h[n] + du * bm[n];
            aa[n] *= dA;
        }
    }
    float* o = agg + (size_t)idx * 8;
#pragma unroll
    for (int n = 0; n < 4; n++) { o[n] = aa[n]; o[4 + n] = h[n]; }
}

__global__ __launch_bounds__(256) void scan_phaseB(const float* __restrict__ agg,
                                                   float* __restrict__ hinit)
{
    int idx = blockIdx.x * 256 + threadIdx.x;
    int d = idx % CDIM;
    int sb = idx / CDIM;
    float st[4] = {0, 0, 0, 0};
    for (int c = 0; c < CH; c++) {
        size_t base = ((size_t)sb * CH + c) * CDIM + d;
        const float* a = agg + base * 8;
        float* hi = hinit + base * 4;
#pragma unroll
        for (int n = 0; n < 4; n++) hi[n] = st[n];
#pragma unroll
        for (int n = 0; n < 4; n++) st[n] = a[n] * st[n] + a[4 + n];
    }
}

__global__ __launch_bounds__(256) void scan_phaseC(
    const float* __restrict__ u0, const float* __restrict__ uz0, const float* __restrict__ dbl0,
    const float* __restrict__ Alog0, const float* __restrict__ Dsk0, unsigned short* __restrict__ g0,
    const float* __restrict__ u1, const float* __restrict__ uz1, const float* __restrict__ dbl1,
    const float* __restrict__ Alog1, const float* __restrict__ Dsk1, unsigned short* __restrict__ g1,
    const float* __restrict__ hinit)
{
    int idx = blockIdx.x * 256 + threadIdx.x;
    int d = idx % CDIM;
    int t1 = idx / CDIM;
    int c = t1 % CH;
    int t2 = t1 / CH;
    int b = t2 & 1;
    int s = t2 >> 1;
    const float* u = s ? u1 : u0;
    const float* uz = s ? uz1 : uz0;
    const float* dbl = s ? dbl1 : dbl0;
    const float* dblO = s ? dbl0 : dbl1;  // cross: other stream's C projection
    const float* Alog = s ? Alog1 : Alog0;
    const float* Dsk = s ? Dsk1 : Dsk0;
    unsigned short* gated = s ? g1 : g0;
    float A[4];
#pragma unroll
    for (int n = 0; n < 4; n++) A[n] = -__expf(Alog[d * 4 + n]);
    float Dv = Dsk[d];
    float h[4];
    const float* hi = hinit + (size_t)idx * 4;
#pragma unroll
    for (int n = 0; n < 4; n++) h[n] = hi[n];
    int rowb = b * LDIM + c * LC;
    for (int t = 0; t < LC; t++) {
        int row = rowb + t;
        float dtv = uz[(size_t)row * (2 * CDIM) + d];        // dt (stored in u-half)
        float uv = u[(size_t)row * CDIM + d];
        float du = dtv * uv;
        const float* bm = dbl + (size_t)row * DBLW + RNK;
        const float* cm = dblO + (size_t)row * DBLW + RNK + NST;
        float y = 0.f;
#pragma unroll
        for (int n = 0; n < 4; n++) {
            float dA = __expf(dtv * A[n]);
            h[n] = dA * h[n] + du * bm[n];
            y += h[n] * cm[n];
        }
        y += uv * Dv;
        float zv = uz[(size_t)row * (2 * CDIM) + CDIM + d];  // z-half
        gated[(size_t)row * CDIM + d] = f2bf(y * (zv * sigmoidf_(zv)));
    }
}

extern "C" void kernel_launch(void* const* d_in, const int* in_sizes, int n_in,
                              void* d_out, int out_size, void* d_ws, size_t ws_size,
                              hipStream_t stream)
{
    const float* x[2] = {(const float*)d_in[0], (const float*)d_in[1]};
    const float *ln_g[2], *ln_b[2], *Win[2], *Wconv[2], *bconv[2], *Wxp[2],
        *Wdt[2], *bdt[2], *Alog[2], *Dskip[2], *Wout[2];
    for (int s = 0; s < 2; s++) {
        int base = 2 + s * 11;
        ln_g[s] = (const float*)d_in[base + 0];
        ln_b[s] = (const float*)d_in[base + 1];
        Win[s] = (const float*)d_in[base + 2];
        Wconv[s] = (const float*)d_in[base + 3];
        bconv[s] = (const float*)d_in[base + 4];
        Wxp[s] = (const float*)d_in[base + 5];
        Wdt[s] = (const float*)d_in[base + 6];
        bdt[s] = (const float*)d_in[base + 7];
        Alog[s] = (const float*)d_in[base + 8];
        Dskip[s] = (const float*)d_in[base + 9];
        Wout[s] = (const float*)d_in[base + 10];
    }

    float* ws = (float*)d_ws;
    const size_t SZ = (size_t)BDIM * LDIM * CDIM;      // 6291456
    const size_t SZ_DBL = (size_t)BDIM * LDIM * DBLW;  // 458752
    float* uz[2] = {ws, ws + 2 * SZ};          // (M,1536); u-half becomes dt after conv
    float* u[2] = {ws + 4 * SZ, ws + 5 * SZ};  // (M,768) fp32
    unsigned short* xnb[2] = {(unsigned short*)(ws + 6 * SZ),
                              (unsigned short*)(ws + 6 * SZ) + SZ};  // bf16 (M,768); reused as gated
    float* dbl[2] = {ws + 7 * SZ, ws + 7 * SZ + SZ_DBL};
    float* p = ws + 7 * SZ + 2 * SZ_DBL;
    unsigned short* WinT[2] = {(unsigned short*)p, (unsigned short*)p + 1536 * 768};
    p += 1536 * 768;  // 2 bf16 arrays of 1536*768 = that many floats
    unsigned short* WoutT[2] = {(unsigned short*)p, (unsigned short*)p + 768 * 768};
    p += 768 * 768;
    float* agg = p;                      // 2*2*64*768*8 = 1572864
    float* hinit = agg + 1572864;        // 786432
    float* stats = hinit + 786432;       // 2*8192*2 = 32768

    const int M = BDIM * LDIM;  // 8192
    dim3 blk(256);

    // LN stats + transpose (also pre-stores residual x into d_out)
    stats_kernel<<<dim3((2 * M) / 256), blk, 0, stream>>>(x[0], x[1], stats);
    transpose_ln_kernel<<<dim3(CDIM / 64, LDIM / 64, 4), blk, 0, stream>>>(
        x[0], x[1], ln_g[0], ln_b[0], ln_g[1], ln_b[1], stats, xnb[0], xnb[1], (float*)d_out);

    // weight transpose/convert to bf16 (N,K)
    for (int s = 0; s < 2; s++) {
        wt_transpose<<<dim3(1536 / 64, 768 / 64), blk, 0, stream>>>(Win[s], WinT[s], CDIM, 2 * CDIM);
        wt_transpose<<<dim3(768 / 64, 768 / 64), blk, 0, stream>>>(Wout[s], WoutT[s], CDIM, CDIM);
    }

    for (int s = 0; s < 2; s++) {
        // in_proj: bf16 MFMA -> uz fp32 (M,1536)
        gemm_mfma<<<dim3(1536 / 128, M / 128), blk, 0, stream>>>(
            xnb[s], WinT[s], uz[s], 2 * CDIM, CDIM, 0);
        // depthwise conv + SiLU -> u fp32
        conv_silu_kernel<<<dim3((M * CDIM) / 256), blk, 0, stream>>>(uz[s], Wconv[s], bconv[s], u[s]);
        // x_proj: u @ Wxp -> dbl (M,56)
        gemm_tiled<<<dim3(1, M / TS), blk, 0, stream>>>(
            u[s], CDIM, Wxp[s], DBLW, dbl[s], DBLW, M, DBLW, CDIM, 0, nullptr);
        // dt = softplus(dtr @ Wdt + bdt) -> into uz u-half (ldc=1536)
        gemm_tiled<<<dim3(CDIM / TS, M / TS), blk, 0, stream>>>(
            dbl[s], DBLW, Wdt[s], CDIM, uz[s], 2 * CDIM, M, CDIM, RNK, 1, bdt[s]);
    }

    // cross selective scan (chunked, 3 phases); gating fused, writes bf16 gated into xnb
    scan_phaseA<<<dim3((2 * BDIM * CH * CDIM) / 256), blk, 0, stream>>>(
        u[0], uz[0], dbl[0], Alog[0], u[1], uz[1], dbl[1], Alog[1], agg);
    scan_phaseB<<<dim3((2 * BDIM * CDIM) / 256), blk, 0, stream>>>(agg, hinit);
    scan_phaseC<<<dim3((2 * BDIM * CH * CDIM) / 256), blk, 0, stream>>>(
        u[0], uz[0], dbl[0], Alog[0], Dskip[0], xnb[0],
        u[1], uz[1], dbl[1], Alog[1], Dskip[1], xnb[1], hinit);

    // out_proj: bf16 MFMA, epi adds into pre-stored residual in d_out
    float* out = (float*)d_out;
    for (int s = 0; s < 2; s++) {
        gemm_mfma<<<dim3(CDIM / 128, M / 128), blk, 0, stream>>>(
            xnb[s], WoutT[s], out + s * SZ, CDIM, CDIM, 1);
    }
}

// Round 3
// 736.563 us; speedup vs baseline: 2.3780x; 1.2024x over previous
//
#include <hip/hip_runtime.h>
#include <cmath>

#define LDIM 4096
#define CDIM 768
#define BDIM 2
#define NST 4
#define RNK 48
#define CH 64     // scan chunks per sequence
#define LC 64     // chunk length (CH*LC == LDIM)

typedef short bf16x8 __attribute__((ext_vector_type(8)));
typedef float f32x4 __attribute__((ext_vector_type(4)));

__device__ __forceinline__ float sigmoidf_(float x) { return 1.f / (1.f + __expf(-x)); }

__device__ __forceinline__ unsigned short f2bf(float f) {
    unsigned int u = __float_as_uint(f);
    u += 0x7fffu + ((u >> 16) & 1u);
    return (unsigned short)(u >> 16);
}
__device__ __forceinline__ float bf2f(unsigned short us) {
    unsigned int u = ((unsigned int)us) << 16;
    return __uint_as_float(u);
}

__device__ __forceinline__ void llds16(const unsigned short* g, unsigned short* l) {
    __builtin_amdgcn_global_load_lds(
        (const __attribute__((address_space(1))) unsigned int*)g,
        (__attribute__((address_space(3))) unsigned int*)l, 16, 0, 0);
}

// ---------- LN stats: mean/rstd per (s,b,l) ----------
__global__ __launch_bounds__(256) void stats_kernel(const float* __restrict__ x0,
                                                    const float* __restrict__ x1,
                                                    float* __restrict__ stats)
{
    int idx = blockIdx.x * 256 + threadIdx.x;  // s*8192 + b*4096 + l
    int s = idx >> 13;
    int bl = idx & 8191;
    int b = bl >> 12, l = bl & (LDIM - 1);
    const float* x = s ? x1 : x0;
    const float* xp = x + (size_t)b * CDIM * LDIM + l;
    float s0 = 0, s1 = 0, q0 = 0, q1 = 0;
    for (int c = 0; c < CDIM; c += 2) {
        float v0 = xp[(size_t)(c + 0) * LDIM];
        float v1 = xp[(size_t)(c + 1) * LDIM];
        s0 += v0; s1 += v1; q0 += v0 * v0; q1 += v1 * v1;
    }
    float m = (s0 + s1) * (1.f / CDIM);
    float var = (q0 + q1) * (1.f / CDIM) - m * m;
    stats[idx * 2] = m;
    stats[idx * 2 + 1] = rsqrtf(var + 1e-5f);
}

// ---------- transpose + LN: x (B,C,L) -> xn bf16 (B*L, C); raw x -> d_out (residual pre-store) ----------
__global__ __launch_bounds__(256) void transpose_ln_kernel(
    const float* __restrict__ x0, const float* __restrict__ x1,
    const float* __restrict__ g0, const float* __restrict__ bb0,
    const float* __restrict__ g1, const float* __restrict__ bb1,
    const float* __restrict__ stats,
    unsigned short* __restrict__ xnb0, unsigned short* __restrict__ xnb1,
    float* __restrict__ out)
{
    __shared__ float tile[64][65];
    int t = threadIdx.x;
    int c0 = blockIdx.x * 64, l0 = blockIdx.y * 64;
    int z = blockIdx.z;
    int s = z >> 1, b = z & 1;
    const float* x = s ? x1 : x0;
    const float* g = s ? g1 : g0;
    const float* bb = s ? bb1 : bb0;
    unsigned short* xnb = s ? xnb1 : xnb0;
    int tl = t & 63, tg = t >> 6;
#pragma unroll
    for (int i = 0; i < 16; i++) {
        int cl = tg * 16 + i;
        tile[cl][tl] = x[((size_t)(b * CDIM + c0 + cl)) * LDIM + l0 + tl];
    }
    __syncthreads();
    const size_t SZ = (size_t)BDIM * LDIM * CDIM;
#pragma unroll
    for (int i = 0; i < 16; i++) {
        int ll = tg * 16 + i;
        int l = l0 + ll, c = c0 + tl;
        float v = tile[tl][ll];
        int sidx = s * 8192 + b * LDIM + l;
        float m = stats[sidx * 2], rs = stats[sidx * 2 + 1];
        size_t o = ((size_t)(b * LDIM + l)) * CDIM + c;
        out[(size_t)s * SZ + o] = v;  // residual pre-store
        xnb[o] = f2bf((v - m) * rs * g[c] + bb[c]);
    }
}

// ---------- weight transpose/convert: W (K,N) fp32 -> Wt (N,K) bf16 ----------
__global__ __launch_bounds__(256) void wt_transpose(const float* __restrict__ W,
                                                    unsigned short* __restrict__ Wt,
                                                    int K, int N)
{
    __shared__ float tile[64][65];
    int t = threadIdx.x;
    int n0 = blockIdx.x * 64, k0 = blockIdx.y * 64;
    int tn = t & 63, tg = t >> 6;
#pragma unroll
    for (int i = 0; i < 16; i++) {
        int kl = tg * 16 + i;
        tile[kl][tn] = W[(size_t)(k0 + kl) * N + n0 + tn];
    }
    __syncthreads();
#pragma unroll
    for (int i = 0; i < 16; i++) {
        int nl = tg * 16 + i;
        int k = k0 + tn, n = n0 + nl;
        Wt[(size_t)n * K + k] = f2bf(tile[tn][nl]);
    }
}

// ---------- Wcomb = Wxp[:, :48] @ Wdt  -> WcombT (N=768, K=768) bf16 ----------
__global__ __launch_bounds__(256) void wcomb_kernel(const float* __restrict__ Wxp,
                                                    const float* __restrict__ Wdt,
                                                    unsigned short* __restrict__ WcombT)
{
    int t = threadIdx.x;
    int k = blockIdx.x * 64 + (t & 63);  // u dim
    int n0 = blockIdx.y * 64;            // dt output col
    float wx[RNK];
#pragma unroll
    for (int r = 0; r < RNK; r++) wx[r] = Wxp[k * 56 + r];
    for (int i = (t >> 6); i < 64; i += 4) {
        int n = n0 + i;
        float acc = 0.f;
#pragma unroll
        for (int r = 0; r < RNK; r++) acc += wx[r] * Wdt[(size_t)r * CDIM + n];
        WcombT[(size_t)n * CDIM + k] = f2bf(acc);
    }
}

// ---------- bf16 MFMA GEMM: C(MxN) fp32 = A(M,K)bf16 @ Bt(N,K)bf16^T ----------
// epi 0: store; epi 1: C += acc (residual pre-stored in C); epi 2: softplus(acc + bias[col])
__global__ __launch_bounds__(256) void gemm_mfma(
    const unsigned short* __restrict__ A, const unsigned short* __restrict__ Bt,
    float* __restrict__ C, int ldc, int K, int epi, const float* __restrict__ bias)
{
    __shared__ unsigned short As[128 * 32];
    __shared__ unsigned short Bs[128 * 32];
    const int tid = threadIdx.x;
    const int wave = tid >> 6, lane = tid & 63;
    const int row0 = blockIdx.y * 128, col0 = blockIdx.x * 128;
    const int wm = (wave >> 1) * 64, wn = (wave & 1) * 64;
    f32x4 acc[4][4] = {};
    const int lr = lane >> 2;
    const int lk = (lane & 3) * 8;
    const int fr = lane & 15, fk = (lane >> 4) * 8;

    for (int k0 = 0; k0 < K; k0 += 32) {
#pragma unroll
        for (int h = 0; h < 2; h++) {
            int rb = wave * 32 + h * 16;
            const unsigned short* ga = A + (size_t)(row0 + rb + lr) * K + k0 + lk;
            const unsigned short* gb = Bt + (size_t)(col0 + rb + lr) * K + k0 + lk;
            llds16(ga, &As[rb * 32]);
            llds16(gb, &Bs[rb * 32]);
        }
        __syncthreads();
        bf16x8 af[4], bfr[4];
#pragma unroll
        for (int i = 0; i < 4; i++)
            af[i] = *(const bf16x8*)&As[(wm + i * 16 + fr) * 32 + fk];
#pragma unroll
        for (int j = 0; j < 4; j++)
            bfr[j] = *(const bf16x8*)&Bs[(wn + j * 16 + fr) * 32 + fk];
#pragma unroll
        for (int i = 0; i < 4; i++)
#pragma unroll
            for (int j = 0; j < 4; j++)
                acc[i][j] = __builtin_amdgcn_mfma_f32_16x16x32_bf16(af[i], bfr[j], acc[i][j], 0, 0, 0);
        __syncthreads();
    }

    const int cr = (lane >> 4) * 4, cc = lane & 15;
#pragma unroll
    for (int i = 0; i < 4; i++)
#pragma unroll
        for (int j = 0; j < 4; j++) {
            int col = col0 + wn + j * 16 + cc;
#pragma unroll
            for (int r = 0; r < 4; r++) {
                int row = row0 + wm + i * 16 + cr + r;
                size_t o = (size_t)row * ldc + col;
                float v = acc[i][j][r];
                if (epi == 1) v += C[o];
                else if (epi == 2) {
                    v += bias[col];
                    v = (v > 20.f) ? v : log1pf(__expf(v));
                }
                C[o] = v;
            }
        }
}

// ---------- depthwise causal conv (K=4) + SiLU; output bf16 ----------
__global__ __launch_bounds__(256) void conv_silu_kernel(const float* __restrict__ uz,
                                                        const float* __restrict__ w,
                                                        const float* __restrict__ bc,
                                                        unsigned short* __restrict__ ub)
{
    int idx = blockIdx.x * 256 + threadIdx.x;  // (b*L + l)*D + d
    int d = idx % CDIM;
    int bl = idx / CDIM;
    int l = bl & (LDIM - 1);
    float acc = bc[d];
    const float* wp = w + d * 4;
#pragma unroll
    for (int k = 0; k < 4; k++) {
        int ls = l - 3 + k;
        if (ls >= 0) acc += uz[(size_t)(bl - 3 + k) * (2 * CDIM) + d] * wp[k];
    }
    ub[idx] = f2bf(acc * sigmoidf_(acc));
}

// ---------- B/C projection GEMV: dbl(M,8) = u @ Wxp[:, 48:56] ----------
__global__ __launch_bounds__(256) void bc_gemv(
    const unsigned short* __restrict__ ub0, const unsigned short* __restrict__ ub1,
    const float* __restrict__ Wxp0, const float* __restrict__ Wxp1,
    float* __restrict__ dbl0, float* __restrict__ dbl1)
{
    int s = blockIdx.y;
    const unsigned short* ub = s ? ub1 : ub0;
    const float* Wxp = s ? Wxp1 : Wxp0;
    float* dbl = s ? dbl1 : dbl0;
    __shared__ float Wl[CDIM][8];
    int t = threadIdx.x;
    for (int i = t; i < CDIM * 8; i += 256) {
        int k = i >> 3, c = i & 7;
        Wl[k][c] = Wxp[k * 56 + RNK + c];
    }
    __syncthreads();
    int c = t & 7;
    int row = blockIdx.x * 32 + (t >> 3);
    const unsigned short* up = ub + (size_t)row * CDIM;
    float acc = 0.f;
    for (int k = 0; k < CDIM; k += 8) {
        bf16x8 uv = *(const bf16x8*)&up[k];
#pragma unroll
        for (int j = 0; j < 8; j++)
            acc += bf2f((unsigned short)uv[j]) * Wl[k + j][c];
    }
    dbl[(size_t)row * 8 + c] = acc;
}

// ---------- chunked selective scan; dt lives in uz[:, :768] (stride 1536), u is bf16 ----------
__global__ __launch_bounds__(256) void scan_phaseA(
    const unsigned short* __restrict__ u0, const float* __restrict__ uz0, const float* __restrict__ dbl0, const float* __restrict__ Alog0,
    const unsigned short* __restrict__ u1, const float* __restrict__ uz1, const float* __restrict__ dbl1, const float* __restrict__ Alog1,
    float* __restrict__ agg)
{
    int idx = blockIdx.x * 256 + threadIdx.x;
    int d = idx % CDIM;
    int t1 = idx / CDIM;
    int c = t1 % CH;
    int t2 = t1 / CH;
    int b = t2 & 1;
    int s = t2 >> 1;
    const unsigned short* u = s ? u1 : u0;
    const float* dt = s ? uz1 : uz0;
    const float* dbl = s ? dbl1 : dbl0;
    const float* Alog = s ? Alog1 : Alog0;
    float A[4];
#pragma unroll
    for (int n = 0; n < 4; n++) A[n] = -__expf(Alog[d * 4 + n]);
    float h[4] = {0, 0, 0, 0}, aa[4] = {1, 1, 1, 1};
    int rowb = b * LDIM + c * LC;
    for (int t = 0; t < LC; t++) {
        int row = rowb + t;
        float dtv = dt[(size_t)row * (2 * CDIM) + d];
        float uv = bf2f(u[(size_t)row * CDIM + d]);
        float du = dtv * uv;
        const float* bm = dbl + (size_t)row * 8;
#pragma unroll
        for (int n = 0; n < 4; n++) {
            float dA = __expf(dtv * A[n]);
            h[n] = dA * h[n] + du * bm[n];
            aa[n] *= dA;
        }
    }
    float* o = agg + (size_t)idx * 8;
#pragma unroll
    for (int n = 0; n < 4; n++) { o[n] = aa[n]; o[4 + n] = h[n]; }
}

__global__ __launch_bounds__(256) void scan_phaseB(const float* __restrict__ agg,
                                                   float* __restrict__ hinit)
{
    int idx = blockIdx.x * 256 + threadIdx.x;
    int d = idx % CDIM;
    int sb = idx / CDIM;
    float st[4] = {0, 0, 0, 0};
    for (int c = 0; c < CH; c++) {
        size_t base = ((size_t)sb * CH + c) * CDIM + d;
        const float* a = agg + base * 8;
        float* hi = hinit + base * 4;
#pragma unroll
        for (int n = 0; n < 4; n++) hi[n] = st[n];
#pragma unroll
        for (int n = 0; n < 4; n++) st[n] = a[n] * st[n] + a[4 + n];
    }
}

__global__ __launch_bounds__(256) void scan_phaseC(
    const unsigned short* __restrict__ u0, const float* __restrict__ uz0, const float* __restrict__ dbl0,
    const float* __restrict__ Alog0, const float* __restrict__ Dsk0, unsigned short* __restrict__ g0,
    const unsigned short* __restrict__ u1, const float* __restrict__ uz1, const float* __restrict__ dbl1,
    const float* __restrict__ Alog1, const float* __restrict__ Dsk1, unsigned short* __restrict__ g1,
    const float* __restrict__ hinit)
{
    int idx = blockIdx.x * 256 + threadIdx.x;
    int d = idx % CDIM;
    int t1 = idx / CDIM;
    int c = t1 % CH;
    int t2 = t1 / CH;
    int b = t2 & 1;
    int s = t2 >> 1;
    const unsigned short* u = s ? u1 : u0;
    const float* uz = s ? uz1 : uz0;
    const float* dbl = s ? dbl1 : dbl0;
    const float* dblO = s ? dbl0 : dbl1;  // cross: other stream's C projection
    const float* Alog = s ? Alog1 : Alog0;
    const float* Dsk = s ? Dsk1 : Dsk0;
    unsigned short* gated = s ? g1 : g0;
    float A[4];
#pragma unroll
    for (int n = 0; n < 4; n++) A[n] = -__expf(Alog[d * 4 + n]);
    float Dv = Dsk[d];
    float h[4];
    const float* hi = hinit + (size_t)idx * 4;
#pragma unroll
    for (int n = 0; n < 4; n++) h[n] = hi[n];
    int rowb = b * LDIM + c * LC;
    for (int t = 0; t < LC; t++) {
        int row = rowb + t;
        float dtv = uz[(size_t)row * (2 * CDIM) + d];        // dt (u-half)
        float uv = bf2f(u[(size_t)row * CDIM + d]);
        float du = dtv * uv;
        const float* bm = dbl + (size_t)row * 8;
        const float* cm = dblO + (size_t)row * 8 + 4;
        float y = 0.f;
#pragma unroll
        for (int n = 0; n < 4; n++) {
            float dA = __expf(dtv * A[n]);
            h[n] = dA * h[n] + du * bm[n];
            y += h[n] * cm[n];
        }
        y += uv * Dv;
        float zv = uz[(size_t)row * (2 * CDIM) + CDIM + d];  // z-half
        gated[(size_t)row * CDIM + d] = f2bf(y * (zv * sigmoidf_(zv)));
    }
}

extern "C" void kernel_launch(void* const* d_in, const int* in_sizes, int n_in,
                              void* d_out, int out_size, void* d_ws, size_t ws_size,
                              hipStream_t stream)
{
    const float* x[2] = {(const float*)d_in[0], (const float*)d_in[1]};
    const float *ln_g[2], *ln_b[2], *Win[2], *Wconv[2], *bconv[2], *Wxp[2],
        *Wdt[2], *bdt[2], *Alog[2], *Dskip[2], *Wout[2];
    for (int s = 0; s < 2; s++) {
        int base = 2 + s * 11;
        ln_g[s] = (const float*)d_in[base + 0];
        ln_b[s] = (const float*)d_in[base + 1];
        Win[s] = (const float*)d_in[base + 2];
        Wconv[s] = (const float*)d_in[base + 3];
        bconv[s] = (const float*)d_in[base + 4];
        Wxp[s] = (const float*)d_in[base + 5];
        Wdt[s] = (const float*)d_in[base + 6];
        bdt[s] = (const float*)d_in[base + 7];
        Alog[s] = (const float*)d_in[base + 8];
        Dskip[s] = (const float*)d_in[base + 9];
        Wout[s] = (const float*)d_in[base + 10];
    }

    float* ws = (float*)d_ws;
    const size_t SZ = (size_t)BDIM * LDIM * CDIM;  // 6291456
    float* uz[2] = {ws, ws + 2 * SZ};              // (M,1536) fp32; u-half becomes dt
    unsigned short* ub[2] = {(unsigned short*)(ws + 4 * SZ),
                             (unsigned short*)(ws + 4 * SZ) + SZ};  // bf16 (M,768)
    unsigned short* xnb[2] = {(unsigned short*)(ws + 5 * SZ),
                              (unsigned short*)(ws + 5 * SZ) + SZ};  // bf16; reused as gated
    float* dbl[2] = {ws + 6 * SZ, ws + 6 * SZ + 65536};              // (M,8) fp32
    float* p = ws + 6 * SZ + 2 * 65536;
    unsigned short* WinT[2] = {(unsigned short*)p, (unsigned short*)p + 1536 * 768};
    p += 1536 * 768;
    unsigned short* WoutT[2] = {(unsigned short*)p, (unsigned short*)p + 768 * 768};
    p += 768 * 768;
    unsigned short* WcombT[2] = {(unsigned short*)p, (unsigned short*)p + 768 * 768};
    p += 768 * 768;
    float* agg = p;                 // 2*2*64*768*8 = 1572864
    float* hinit = agg + 1572864;   // 786432
    float* stats = hinit + 786432;  // 32768

    const int M = BDIM * LDIM;  // 8192
    dim3 blk(256);

    // LN stats + transpose (pre-stores residual into d_out)
    stats_kernel<<<dim3((2 * M) / 256), blk, 0, stream>>>(x[0], x[1], stats);
    transpose_ln_kernel<<<dim3(CDIM / 64, LDIM / 64, 4), blk, 0, stream>>>(
        x[0], x[1], ln_g[0], ln_b[0], ln_g[1], ln_b[1], stats, xnb[0], xnb[1], (float*)d_out);

    // weight prep
    for (int s = 0; s < 2; s++) {
        wt_transpose<<<dim3(1536 / 64, 768 / 64), blk, 0, stream>>>(Win[s], WinT[s], CDIM, 2 * CDIM);
        wt_transpose<<<dim3(768 / 64, 768 / 64), blk, 0, stream>>>(Wout[s], WoutT[s], CDIM, CDIM);
        wcomb_kernel<<<dim3(768 / 64, 768 / 64), blk, 0, stream>>>(Wxp[s], Wdt[s], WcombT[s]);
    }

    for (int s = 0; s < 2; s++) {
        // in_proj: bf16 MFMA -> uz fp32 (M,1536)
        gemm_mfma<<<dim3(1536 / 128, M / 128), blk, 0, stream>>>(
            xnb[s], WinT[s], uz[s], 2 * CDIM, CDIM, 0, nullptr);
        // depthwise conv + SiLU -> ub bf16
        conv_silu_kernel<<<dim3((M * CDIM) / 256), blk, 0, stream>>>(uz[s], Wconv[s], bconv[s], ub[s]);
        // dt = softplus(u @ Wcomb + bdt) -> uz u-half (ldc=1536)
        gemm_mfma<<<dim3(CDIM / 128, M / 128), blk, 0, stream>>>(
            ub[s], WcombT[s], uz[s], 2 * CDIM, CDIM, 2, bdt[s]);
    }

    // B/C projection for both streams
    bc_gemv<<<dim3(M / 32, 2), blk, 0, stream>>>(ub[0], ub[1], Wxp[0], Wxp[1], dbl[0], dbl[1]);

    // cross selective scan (3 phases); gating fused, writes bf16 gated into xnb
    scan_phaseA<<<dim3((2 * BDIM * CH * CDIM) / 256), blk, 0, stream>>>(
        ub[0], uz[0], dbl[0], Alog[0], ub[1], uz[1], dbl[1], Alog[1], agg);
    scan_phaseB<<<dim3((2 * BDIM * CDIM) / 256), blk, 0, stream>>>(agg, hinit);
    scan_phaseC<<<dim3((2 * BDIM * CH * CDIM) / 256), blk, 0, stream>>>(
        ub[0], uz[0], dbl[0], Alog[0], Dskip[0], xnb[0],
        ub[1], uz[1], dbl[1], Alog[1], Dskip[1], xnb[1], hinit);

    // out_proj: bf16 MFMA, adds into pre-stored residual in d_out
    float* out = (float*)d_out;
    for (int s = 0; s < 2; s++) {
        gemm_mfma<<<dim3(CDIM / 128, M / 128), blk, 0, stream>>>(
            xnb[s], WoutT[s], out + s * SZ, CDIM, CDIM, 1, nullptr);
    }
}

// Round 4
// 670.774 us; speedup vs baseline: 2.6112x; 1.0981x over previous
//
#include <hip/hip_runtime.h>
#include <cmath>

#define LDIM 4096
#define CDIM 768
#define BDIM 2
#define NST 4
#define RNK 48
#define CH 64     // scan chunks per sequence
#define LC 64     // chunk length (CH*LC == LDIM)

typedef short bf16x8 __attribute__((ext_vector_type(8)));
typedef float f32x4 __attribute__((ext_vector_type(4)));
typedef unsigned short ushort_t;

__device__ __forceinline__ float sigmoidf_(float x) { return 1.f / (1.f + __expf(-x)); }

__device__ __forceinline__ unsigned short f2bf(float f) {
    unsigned int u = __float_as_uint(f);
    u += 0x7fffu + ((u >> 16) & 1u);
    return (unsigned short)(u >> 16);
}
__device__ __forceinline__ float bf2f(unsigned short us) {
    unsigned int u = ((unsigned int)us) << 16;
    return __uint_as_float(u);
}

__device__ __forceinline__ void llds16(const unsigned short* g, unsigned short* l) {
    __builtin_amdgcn_global_load_lds(
        (const __attribute__((address_space(1))) unsigned int*)g,
        (__attribute__((address_space(3))) unsigned int*)l, 16, 0, 0);
}

// ---------- LN stats: 256 blocks, 4 waves split C, LDS reduce ----------
__global__ __launch_bounds__(256) void stats_kernel(const float* __restrict__ x0,
                                                    const float* __restrict__ x1,
                                                    float* __restrict__ stats)
{
    int blk = blockIdx.x;  // 0..255: s(1) b(1) lgroup(6)
    int s = blk >> 7;
    int b = (blk >> 6) & 1;
    int l0 = (blk & 63) * 64;
    int wave = threadIdx.x >> 6, lane = threadIdx.x & 63;
    const float* x = s ? x1 : x0;
    const float* xp = x + ((size_t)b * CDIM) * LDIM + l0 + lane;
    float sm = 0.f, sq = 0.f;
    int cbeg = wave * 192;
#pragma unroll 4
    for (int i = 0; i < 192; i++) {
        float v = xp[(size_t)(cbeg + i) * LDIM];
        sm += v; sq += v * v;
    }
    __shared__ float red[2][4][64];
    red[0][wave][lane] = sm;
    red[1][wave][lane] = sq;
    __syncthreads();
    if (wave == 0) {
        float s_ = red[0][0][lane] + red[0][1][lane] + red[0][2][lane] + red[0][3][lane];
        float q_ = red[1][0][lane] + red[1][1][lane] + red[1][2][lane] + red[1][3][lane];
        float m = s_ * (1.f / CDIM);
        float var = q_ * (1.f / CDIM) - m * m;
        int idx = s * 8192 + b * LDIM + l0 + lane;
        stats[2 * idx] = m;
        stats[2 * idx + 1] = rsqrtf(var + 1e-5f);
    }
}

// ---------- transpose + LN: x (B,C,L) -> xn bf16 (B*L, C); raw x -> d_out (residual pre-store) ----------
__global__ __launch_bounds__(256) void transpose_ln_kernel(
    const float* __restrict__ x0, const float* __restrict__ x1,
    const float* __restrict__ g0, const float* __restrict__ bb0,
    const float* __restrict__ g1, const float* __restrict__ bb1,
    const float* __restrict__ stats,
    unsigned short* __restrict__ xnb0, unsigned short* __restrict__ xnb1,
    float* __restrict__ out)
{
    __shared__ float tile[64][65];
    int t = threadIdx.x;
    int c0 = blockIdx.x * 64, l0 = blockIdx.y * 64;
    int z = blockIdx.z;
    int s = z >> 1, b = z & 1;
    const float* x = s ? x1 : x0;
    const float* g = s ? g1 : g0;
    const float* bb = s ? bb1 : bb0;
    unsigned short* xnb = s ? xnb1 : xnb0;
    int tl = t & 63, tg = t >> 6;
#pragma unroll
    for (int i = 0; i < 16; i++) {
        int cl = tg * 16 + i;
        tile[cl][tl] = x[((size_t)(b * CDIM + c0 + cl)) * LDIM + l0 + tl];
    }
    __syncthreads();
    const size_t SZ = (size_t)BDIM * LDIM * CDIM;
#pragma unroll
    for (int i = 0; i < 16; i++) {
        int ll = tg * 16 + i;
        int l = l0 + ll, c = c0 + tl;
        float v = tile[tl][ll];
        int sidx = s * 8192 + b * LDIM + l;
        float m = stats[sidx * 2], rs = stats[sidx * 2 + 1];
        size_t o = ((size_t)(b * LDIM + l)) * CDIM + c;
        out[(size_t)s * SZ + o] = v;  // residual pre-store
        xnb[o] = f2bf((v - m) * rs * g[c] + bb[c]);
    }
}

// ---------- weight transpose/convert: W (K,N) fp32 -> Wt (N,K) bf16 ----------
__global__ __launch_bounds__(256) void wt_transpose(const float* __restrict__ W,
                                                    unsigned short* __restrict__ Wt,
                                                    int K, int N)
{
    __shared__ float tile[64][65];
    int t = threadIdx.x;
    int n0 = blockIdx.x * 64, k0 = blockIdx.y * 64;
    int tn = t & 63, tg = t >> 6;
#pragma unroll
    for (int i = 0; i < 16; i++) {
        int kl = tg * 16 + i;
        tile[kl][tn] = W[(size_t)(k0 + kl) * N + n0 + tn];
    }
    __syncthreads();
#pragma unroll
    for (int i = 0; i < 16; i++) {
        int nl = tg * 16 + i;
        int k = k0 + tn, n = n0 + nl;
        Wt[(size_t)n * K + k] = f2bf(tile[tn][nl]);
    }
}

// ---------- Wcomb = Wxp[:, :48] @ Wdt  -> WcombT (N=768, K=768) bf16 ----------
__global__ __launch_bounds__(256) void wcomb_kernel(const float* __restrict__ Wxp,
                                                    const float* __restrict__ Wdt,
                                                    unsigned short* __restrict__ WcombT)
{
    int t = threadIdx.x;
    int k = blockIdx.x * 64 + (t & 63);
    int n0 = blockIdx.y * 64;
    float wx[RNK];
#pragma unroll
    for (int r = 0; r < RNK; r++) wx[r] = Wxp[k * 56 + r];
    for (int i = (t >> 6); i < 64; i += 4) {
        int n = n0 + i;
        float acc = 0.f;
#pragma unroll
        for (int r = 0; r < RNK; r++) acc += wx[r] * Wdt[(size_t)r * CDIM + n];
        WcombT[(size_t)n * CDIM + k] = f2bf(acc);
    }
}

// ---------- bf16 MFMA GEMM, 2 streams via blockIdx.z, XOR-swizzled LDS ----------
// epi 1: fp32 C += acc (residual pre-stored); epi 2: bf16 softplus(acc+bias); epi 3: bf16 store
__global__ __launch_bounds__(256) void gemm_mfma(
    const unsigned short* __restrict__ A0, const unsigned short* __restrict__ A1,
    const unsigned short* __restrict__ Bt0, const unsigned short* __restrict__ Bt1,
    void* __restrict__ C0, void* __restrict__ C1, int ldc, int K, int epi,
    const float* __restrict__ bias0, const float* __restrict__ bias1)
{
    const unsigned short* A = blockIdx.z ? A1 : A0;
    const unsigned short* Bt = blockIdx.z ? Bt1 : Bt0;
    void* C = blockIdx.z ? C1 : C0;
    const float* bias = blockIdx.z ? bias1 : bias0;

    __shared__ unsigned short As[128 * 32];
    __shared__ unsigned short Bs[128 * 32];
    const int tid = threadIdx.x;
    const int wave = tid >> 6, lane = tid & 63;
    const int row0 = blockIdx.y * 128, col0 = blockIdx.x * 128;
    const int wm = (wave >> 1) * 64, wn = (wave & 1) * 64;
    f32x4 acc[4][4] = {};
    const int lr = lane >> 2;                                // staging row within 16
    const int gi = ((lane & 3) ^ ((lane >> 3) & 3)) * 8;     // swizzled global k-chunk
    const int fr = lane & 15, fc = lane >> 4;                // fragment row / k-chunk

    for (int k0 = 0; k0 < K; k0 += 32) {
#pragma unroll
        for (int h = 0; h < 2; h++) {
            int rb = wave * 32 + h * 16;
            const unsigned short* ga = A + (size_t)(row0 + rb + lr) * K + k0 + gi;
            const unsigned short* gb = Bt + (size_t)(col0 + rb + lr) * K + k0 + gi;
            llds16(ga, &As[rb * 32]);
            llds16(gb, &Bs[rb * 32]);
        }
        __syncthreads();
        bf16x8 af[4], bfr[4];
#pragma unroll
        for (int i = 0; i < 4; i++) {
            int r = wm + i * 16 + fr;
            af[i] = *(const bf16x8*)&As[r * 32 + (fc ^ ((r >> 1) & 3)) * 8];
        }
#pragma unroll
        for (int j = 0; j < 4; j++) {
            int r = wn + j * 16 + fr;
            bfr[j] = *(const bf16x8*)&Bs[r * 32 + (fc ^ ((r >> 1) & 3)) * 8];
        }
#pragma unroll
        for (int i = 0; i < 4; i++)
#pragma unroll
            for (int j = 0; j < 4; j++)
                acc[i][j] = __builtin_amdgcn_mfma_f32_16x16x32_bf16(af[i], bfr[j], acc[i][j], 0, 0, 0);
        __syncthreads();
    }

    const int cr = (lane >> 4) * 4, cc = lane & 15;
#pragma unroll
    for (int i = 0; i < 4; i++)
#pragma unroll
        for (int j = 0; j < 4; j++) {
            int col = col0 + wn + j * 16 + cc;
#pragma unroll
            for (int r = 0; r < 4; r++) {
                int row = row0 + wm + i * 16 + cr + r;
                size_t o = (size_t)row * ldc + col;
                float v = acc[i][j][r];
                if (epi == 1) {
                    float* Cf = (float*)C;
                    Cf[o] = v + Cf[o];
                } else if (epi == 2) {
                    v += bias[col];
                    v = (v > 20.f) ? v : log1pf(__expf(v));
                    ((unsigned short*)C)[o] = f2bf(v);
                } else {
                    ((unsigned short*)C)[o] = f2bf(v);
                }
            }
        }
}

// ---------- depthwise causal conv (K=4) + SiLU; bf16 in (stride 1536), bf16 out; 4 d's/thread ----------
__global__ __launch_bounds__(256) void conv_silu_kernel(
    const unsigned short* __restrict__ uzb0, const unsigned short* __restrict__ uzb1,
    const float* __restrict__ w0, const float* __restrict__ bc0,
    const float* __restrict__ w1, const float* __restrict__ bc1,
    unsigned short* __restrict__ ub0, unsigned short* __restrict__ ub1)
{
    int s = blockIdx.y;
    const unsigned short* uzb = s ? uzb1 : uzb0;
    const float* w = s ? w1 : w0;
    const float* bc = s ? bc1 : bc0;
    unsigned short* ub = s ? ub1 : ub0;
    int idx = blockIdx.x * 256 + threadIdx.x;  // over M*CDIM/4
    int d4 = (idx % 192) * 4;
    int bl = idx / 192;
    int l = bl & (LDIM - 1);
    float acc[4];
#pragma unroll
    for (int j = 0; j < 4; j++) acc[j] = bc[d4 + j];
#pragma unroll
    for (int k = 0; k < 4; k++) {
        int ls = l - 3 + k;
        if (ls >= 0) {
            const unsigned short* rp = uzb + (size_t)(bl - 3 + k) * (2 * CDIM) + d4;
#pragma unroll
            for (int j = 0; j < 4; j++)
                acc[j] += bf2f(rp[j]) * w[(d4 + j) * 4 + k];
        }
    }
    unsigned short* op = ub + (size_t)bl * CDIM + d4;
#pragma unroll
    for (int j = 0; j < 4; j++) {
        float v = acc[j];
        op[j] = f2bf(v * sigmoidf_(v));
    }
}

// ---------- B/C projection GEMV: dbl(M,8) = u @ Wxp[:, 48:56] ----------
__global__ __launch_bounds__(256) void bc_gemv(
    const unsigned short* __restrict__ ub0, const unsigned short* __restrict__ ub1,
    const float* __restrict__ Wxp0, const float* __restrict__ Wxp1,
    float* __restrict__ dbl0, float* __restrict__ dbl1)
{
    int s = blockIdx.y;
    const unsigned short* ub = s ? ub1 : ub0;
    const float* Wxp = s ? Wxp1 : Wxp0;
    float* dbl = s ? dbl1 : dbl0;
    __shared__ float Wl[CDIM][8];
    int t = threadIdx.x;
    for (int i = t; i < CDIM * 8; i += 256) {
        int k = i >> 3, c = i & 7;
        Wl[k][c] = Wxp[k * 56 + RNK + c];
    }
    __syncthreads();
    int c = t & 7;
    int row = blockIdx.x * 32 + (t >> 3);
    const unsigned short* up = ub + (size_t)row * CDIM;
    float acc = 0.f;
    for (int k = 0; k < CDIM; k += 8) {
        bf16x8 uv = *(const bf16x8*)&up[k];
#pragma unroll
        for (int j = 0; j < 8; j++)
            acc += bf2f((unsigned short)uv[j]) * Wl[k + j][c];
    }
    dbl[(size_t)row * 8 + c] = acc;
}

// ---------- chunked selective scan; u/dt/z all bf16 ----------
__global__ __launch_bounds__(256) void scan_phaseA(
    const unsigned short* __restrict__ u0, const unsigned short* __restrict__ dt0,
    const float* __restrict__ dbl0, const float* __restrict__ Alog0,
    const unsigned short* __restrict__ u1, const unsigned short* __restrict__ dt1,
    const float* __restrict__ dbl1, const float* __restrict__ Alog1,
    float* __restrict__ agg)
{
    int idx = blockIdx.x * 256 + threadIdx.x;
    int d = idx % CDIM;
    int t1 = idx / CDIM;
    int c = t1 % CH;
    int t2 = t1 / CH;
    int b = t2 & 1;
    int s = t2 >> 1;
    const unsigned short* u = s ? u1 : u0;
    const unsigned short* dt = s ? dt1 : dt0;
    const float* dbl = s ? dbl1 : dbl0;
    const float* Alog = s ? Alog1 : Alog0;
    float A[4];
#pragma unroll
    for (int n = 0; n < 4; n++) A[n] = -__expf(Alog[d * 4 + n]);
    float h[4] = {0, 0, 0, 0}, aa[4] = {1, 1, 1, 1};
    int rowb = b * LDIM + c * LC;
    for (int t = 0; t < LC; t++) {
        int row = rowb + t;
        float dtv = bf2f(dt[(size_t)row * CDIM + d]);
        float uv = bf2f(u[(size_t)row * CDIM + d]);
        float du = dtv * uv;
        const float* bm = dbl + (size_t)row * 8;
#pragma unroll
        for (int n = 0; n < 4; n++) {
            float dA = __expf(dtv * A[n]);
            h[n] = dA * h[n] + du * bm[n];
            aa[n] *= dA;
        }
    }
    float* o = agg + (size_t)idx * 8;
#pragma unroll
    for (int n = 0; n < 4; n++) { o[n] = aa[n]; o[4 + n] = h[n]; }
}

__global__ __launch_bounds__(256) void scan_phaseB(const float* __restrict__ agg,
                                                   float* __restrict__ hinit)
{
    int idx = blockIdx.x * 256 + threadIdx.x;
    int d = idx % CDIM;
    int sb = idx / CDIM;
    float st[4] = {0, 0, 0, 0};
    for (int c = 0; c < CH; c++) {
        size_t base = ((size_t)sb * CH + c) * CDIM + d;
        const float* a = agg + base * 8;
        float* hi = hinit + base * 4;
#pragma unroll
        for (int n = 0; n < 4; n++) hi[n] = st[n];
#pragma unroll
        for (int n = 0; n < 4; n++) st[n] = a[n] * st[n] + a[4 + n];
    }
}

__global__ __launch_bounds__(256) void scan_phaseC(
    const unsigned short* __restrict__ u0, const unsigned short* __restrict__ dt0,
    const unsigned short* __restrict__ uzb0, const float* __restrict__ dbl0,
    const float* __restrict__ Alog0, const float* __restrict__ Dsk0, unsigned short* __restrict__ g0,
    const unsigned short* __restrict__ u1, const unsigned short* __restrict__ dt1,
    const unsigned short* __restrict__ uzb1, const float* __restrict__ dbl1,
    const float* __restrict__ Alog1, const float* __restrict__ Dsk1, unsigned short* __restrict__ g1,
    const float* __restrict__ hinit)
{
    int idx = blockIdx.x * 256 + threadIdx.x;
    int d = idx % CDIM;
    int t1 = idx / CDIM;
    int c = t1 % CH;
    int t2 = t1 / CH;
    int b = t2 & 1;
    int s = t2 >> 1;
    const unsigned short* u = s ? u1 : u0;
    const unsigned short* dt = s ? dt1 : dt0;
    const unsigned short* uzb = s ? uzb1 : uzb0;
    const float* dbl = s ? dbl1 : dbl0;
    const float* dblO = s ? dbl0 : dbl1;  // cross: other stream's C projection
    const float* Alog = s ? Alog1 : Alog0;
    const float* Dsk = s ? Dsk1 : Dsk0;
    unsigned short* gated = s ? g1 : g0;
    float A[4];
#pragma unroll
    for (int n = 0; n < 4; n++) A[n] = -__expf(Alog[d * 4 + n]);
    float Dv = Dsk[d];
    float h[4];
    const float* hi = hinit + (size_t)idx * 4;
#pragma unroll
    for (int n = 0; n < 4; n++) h[n] = hi[n];
    int rowb = b * LDIM + c * LC;
    for (int t = 0; t < LC; t++) {
        int row = rowb + t;
        float dtv = bf2f(dt[(size_t)row * CDIM + d]);
        float uv = bf2f(u[(size_t)row * CDIM + d]);
        float du = dtv * uv;
        const float* bm = dbl + (size_t)row * 8;
        const float* cm = dblO + (size_t)row * 8 + 4;
        float y = 0.f;
#pragma unroll
        for (int n = 0; n < 4; n++) {
            float dA = __expf(dtv * A[n]);
            h[n] = dA * h[n] + du * bm[n];
            y += h[n] * cm[n];
        }
        y += uv * Dv;
        float zv = bf2f(uzb[(size_t)row * (2 * CDIM) + CDIM + d]);
        gated[(size_t)row * CDIM + d] = f2bf(y * (zv * sigmoidf_(zv)));
    }
}

extern "C" void kernel_launch(void* const* d_in, const int* in_sizes, int n_in,
                              void* d_out, int out_size, void* d_ws, size_t ws_size,
                              hipStream_t stream)
{
    const float* x[2] = {(const float*)d_in[0], (const float*)d_in[1]};
    const float *ln_g[2], *ln_b[2], *Win[2], *Wconv[2], *bconv[2], *Wxp[2],
        *Wdt[2], *bdt[2], *Alog[2], *Dskip[2], *Wout[2];
    for (int s = 0; s < 2; s++) {
        int base = 2 + s * 11;
        ln_g[s] = (const float*)d_in[base + 0];
        ln_b[s] = (const float*)d_in[base + 1];
        Win[s] = (const float*)d_in[base + 2];
        Wconv[s] = (const float*)d_in[base + 3];
        bconv[s] = (const float*)d_in[base + 4];
        Wxp[s] = (const float*)d_in[base + 5];
        Wdt[s] = (const float*)d_in[base + 6];
        bdt[s] = (const float*)d_in[base + 7];
        Alog[s] = (const float*)d_in[base + 8];
        Dskip[s] = (const float*)d_in[base + 9];
        Wout[s] = (const float*)d_in[base + 10];
    }

    const int M = BDIM * LDIM;  // 8192
    char* base = (char*)d_ws;
    auto alloc = [&](size_t bytes) {
        char* p = base;
        base += (bytes + 255) & ~(size_t)255;
        return p;
    };
    unsigned short* uzb[2] = {(unsigned short*)alloc((size_t)M * 1536 * 2),
                              (unsigned short*)alloc((size_t)M * 1536 * 2)};
    unsigned short* dtb[2] = {(unsigned short*)alloc((size_t)M * CDIM * 2),
                              (unsigned short*)alloc((size_t)M * CDIM * 2)};
    unsigned short* ub[2] = {(unsigned short*)alloc((size_t)M * CDIM * 2),
                             (unsigned short*)alloc((size_t)M * CDIM * 2)};
    unsigned short* xnb[2] = {(unsigned short*)alloc((size_t)M * CDIM * 2),
                              (unsigned short*)alloc((size_t)M * CDIM * 2)};  // reused as gated
    float* dbl[2] = {(float*)alloc((size_t)M * 8 * 4), (float*)alloc((size_t)M * 8 * 4)};
    unsigned short* WinT[2] = {(unsigned short*)alloc(1536 * 768 * 2),
                               (unsigned short*)alloc(1536 * 768 * 2)};
    unsigned short* WoutT[2] = {(unsigned short*)alloc(768 * 768 * 2),
                                (unsigned short*)alloc(768 * 768 * 2)};
    unsigned short* WcombT[2] = {(unsigned short*)alloc(768 * 768 * 2),
                                 (unsigned short*)alloc(768 * 768 * 2)};
    float* agg = (float*)alloc((size_t)2 * BDIM * CH * CDIM * 8 * 4);
    float* hinit = (float*)alloc((size_t)2 * BDIM * CH * CDIM * 4 * 4);
    float* stats = (float*)alloc((size_t)2 * M * 2 * 4);

    dim3 blk(256);
    const size_t SZ = (size_t)BDIM * LDIM * CDIM;

    // LN stats + transpose (pre-stores residual into d_out)
    stats_kernel<<<dim3(256), blk, 0, stream>>>(x[0], x[1], stats);
    transpose_ln_kernel<<<dim3(CDIM / 64, LDIM / 64, 4), blk, 0, stream>>>(
        x[0], x[1], ln_g[0], ln_b[0], ln_g[1], ln_b[1], stats, xnb[0], xnb[1], (float*)d_out);

    // weight prep
    for (int s = 0; s < 2; s++) {
        wt_transpose<<<dim3(1536 / 64, 768 / 64), blk, 0, stream>>>(Win[s], WinT[s], CDIM, 2 * CDIM);
        wt_transpose<<<dim3(768 / 64, 768 / 64), blk, 0, stream>>>(Wout[s], WoutT[s], CDIM, CDIM);
        wcomb_kernel<<<dim3(768 / 64, 768 / 64), blk, 0, stream>>>(Wxp[s], Wdt[s], WcombT[s]);
    }

    // in_proj (both streams): bf16 MFMA -> uzb bf16 (M,1536)
    gemm_mfma<<<dim3(1536 / 128, M / 128, 2), blk, 0, stream>>>(
        xnb[0], xnb[1], WinT[0], WinT[1], uzb[0], uzb[1], 2 * CDIM, CDIM, 3, nullptr, nullptr);

    // depthwise conv + SiLU (both streams) -> ub bf16
    conv_silu_kernel<<<dim3((M * CDIM / 4) / 256, 2), blk, 0, stream>>>(
        uzb[0], uzb[1], Wconv[0], bconv[0], Wconv[1], bconv[1], ub[0], ub[1]);

    // dt = softplus(u @ Wcomb + bdt) -> dtb bf16 (both streams)
    gemm_mfma<<<dim3(CDIM / 128, M / 128, 2), blk, 0, stream>>>(
        ub[0], ub[1], WcombT[0], WcombT[1], dtb[0], dtb[1], CDIM, CDIM, 2, bdt[0], bdt[1]);

    // B/C projection for both streams
    bc_gemv<<<dim3(M / 32, 2), blk, 0, stream>>>(ub[0], ub[1], Wxp[0], Wxp[1], dbl[0], dbl[1]);

    // cross selective scan (3 phases); gating fused, writes bf16 gated into xnb
    scan_phaseA<<<dim3((2 * BDIM * CH * CDIM) / 256), blk, 0, stream>>>(
        ub[0], dtb[0], dbl[0], Alog[0], ub[1], dtb[1], dbl[1], Alog[1], agg);
    scan_phaseB<<<dim3((2 * BDIM * CDIM) / 256), blk, 0, stream>>>(agg, hinit);
    scan_phaseC<<<dim3((2 * BDIM * CH * CDIM) / 256), blk, 0, stream>>>(
        ub[0], dtb[0], uzb[0], dbl[0], Alog[0], Dskip[0], xnb[0],
        ub[1], dtb[1], uzb[1], dbl[1], Alog[1], Dskip[1], xnb[1], hinit);

    // out_proj (both streams): bf16 MFMA, adds into pre-stored residual in d_out
    float* out = (float*)d_out;
    gemm_mfma<<<dim3(CDIM / 128, M / 128, 2), blk, 0, stream>>>(
        xnb[0], xnb[1], WoutT[0], WoutT[1], out, out + SZ, CDIM, CDIM, 1, nullptr, nullptr);
}

// Round 5
// 605.155 us; speedup vs baseline: 2.8944x; 1.1084x over previous
//
#include <hip/hip_runtime.h>
#include <cmath>

#define LDIM 4096
#define CDIM 768
#define BDIM 2
#define NST 4
#define RNK 48
#define CH 64     // scan chunks per sequence
#define LC 64     // chunk length (CH*LC == LDIM)

typedef short bf16x8 __attribute__((ext_vector_type(8)));
typedef float f32x4 __attribute__((ext_vector_type(4)));

__device__ __forceinline__ float sigmoidf_(float x) { return 1.f / (1.f + __expf(-x)); }

__device__ __forceinline__ unsigned short f2bf(float f) {
    unsigned int u = __float_as_uint(f);
    u += 0x7fffu + ((u >> 16) & 1u);
    return (unsigned short)(u >> 16);
}
__device__ __forceinline__ float bf2f(unsigned short us) {
    unsigned int u = ((unsigned int)us) << 16;
    return __uint_as_float(u);
}

__device__ __forceinline__ void llds16(const unsigned short* g, unsigned short* l) {
    __builtin_amdgcn_global_load_lds(
        (const __attribute__((address_space(1))) unsigned int*)g,
        (__attribute__((address_space(3))) unsigned int*)l, 16, 0, 0);
}

// ---------- LN stats: 256 blocks, 4 waves split C, LDS reduce ----------
__global__ __launch_bounds__(256) void stats_kernel(const float* __restrict__ x0,
                                                    const float* __restrict__ x1,
                                                    float* __restrict__ stats)
{
    int blk = blockIdx.x;  // 0..255: s(1) b(1) lgroup(6)
    int s = blk >> 7;
    int b = (blk >> 6) & 1;
    int l0 = (blk & 63) * 64;
    int wave = threadIdx.x >> 6, lane = threadIdx.x & 63;
    const float* x = s ? x1 : x0;
    const float* xp = x + ((size_t)b * CDIM) * LDIM + l0 + lane;
    float sm = 0.f, sq = 0.f;
    int cbeg = wave * 192;
#pragma unroll 4
    for (int i = 0; i < 192; i++) {
        float v = xp[(size_t)(cbeg + i) * LDIM];
        sm += v; sq += v * v;
    }
    __shared__ float red[2][4][64];
    red[0][wave][lane] = sm;
    red[1][wave][lane] = sq;
    __syncthreads();
    if (wave == 0) {
        float s_ = red[0][0][lane] + red[0][1][lane] + red[0][2][lane] + red[0][3][lane];
        float q_ = red[1][0][lane] + red[1][1][lane] + red[1][2][lane] + red[1][3][lane];
        float m = s_ * (1.f / CDIM);
        float var = q_ * (1.f / CDIM) - m * m;
        int idx = s * 8192 + b * LDIM + l0 + lane;
        stats[2 * idx] = m;
        stats[2 * idx + 1] = rsqrtf(var + 1e-5f);
    }
}

// ---------- transpose + LN: x (B,C,L) -> xn bf16 (B*L, C); raw x -> d_out (residual pre-store) ----------
__global__ __launch_bounds__(256) void transpose_ln_kernel(
    const float* __restrict__ x0, const float* __restrict__ x1,
    const float* __restrict__ g0, const float* __restrict__ bb0,
    const float* __restrict__ g1, const float* __restrict__ bb1,
    const float* __restrict__ stats,
    unsigned short* __restrict__ xnb0, unsigned short* __restrict__ xnb1,
    float* __restrict__ out)
{
    __shared__ float tile[64][65];
    int t = threadIdx.x;
    int c0 = blockIdx.x * 64, l0 = blockIdx.y * 64;
    int z = blockIdx.z;
    int s = z >> 1, b = z & 1;
    const float* x = s ? x1 : x0;
    const float* g = s ? g1 : g0;
    const float* bb = s ? bb1 : bb0;
    unsigned short* xnb = s ? xnb1 : xnb0;
    int tl = t & 63, tg = t >> 6;
#pragma unroll
    for (int i = 0; i < 16; i++) {
        int cl = tg * 16 + i;
        tile[cl][tl] = x[((size_t)(b * CDIM + c0 + cl)) * LDIM + l0 + tl];
    }
    __syncthreads();
    const size_t SZ = (size_t)BDIM * LDIM * CDIM;
#pragma unroll
    for (int i = 0; i < 16; i++) {
        int ll = tg * 16 + i;
        int l = l0 + ll, c = c0 + tl;
        float v = tile[tl][ll];
        int sidx = s * 8192 + b * LDIM + l;
        float m = stats[sidx * 2], rs = stats[sidx * 2 + 1];
        size_t o = ((size_t)(b * LDIM + l)) * CDIM + c;
        out[(size_t)s * SZ + o] = v;  // residual pre-store
        xnb[o] = f2bf((v - m) * rs * g[c] + bb[c]);
    }
}

// ---------- weight transpose/convert: W (K,N) fp32 -> Wt (N,K) bf16 ----------
__global__ __launch_bounds__(256) void wt_transpose(const float* __restrict__ W,
                                                    unsigned short* __restrict__ Wt,
                                                    int K, int N)
{
    __shared__ float tile[64][65];
    int t = threadIdx.x;
    int n0 = blockIdx.x * 64, k0 = blockIdx.y * 64;
    int tn = t & 63, tg = t >> 6;
#pragma unroll
    for (int i = 0; i < 16; i++) {
        int kl = tg * 16 + i;
        tile[kl][tn] = W[(size_t)(k0 + kl) * N + n0 + tn];
    }
    __syncthreads();
#pragma unroll
    for (int i = 0; i < 16; i++) {
        int nl = tg * 16 + i;
        int k = k0 + tn, n = n0 + nl;
        Wt[(size_t)n * K + k] = f2bf(tile[tn][nl]);
    }
}

// ---------- Wcomb = Wxp[:, :48] @ Wdt  -> WcombT (N=768, K=768) bf16 ----------
__global__ __launch_bounds__(256) void wcomb_kernel(const float* __restrict__ Wxp,
                                                    const float* __restrict__ Wdt,
                                                    unsigned short* __restrict__ WcombT)
{
    int t = threadIdx.x;
    int k = blockIdx.x * 64 + (t & 63);
    int n0 = blockIdx.y * 64;
    float wx[RNK];
#pragma unroll
    for (int r = 0; r < RNK; r++) wx[r] = Wxp[k * 56 + r];
    for (int i = (t >> 6); i < 64; i += 4) {
        int n = n0 + i;
        float acc = 0.f;
#pragma unroll
        for (int r = 0; r < RNK; r++) acc += wx[r] * Wdt[(size_t)r * CDIM + n];
        WcombT[(size_t)n * CDIM + k] = f2bf(acc);
    }
}

// ---------- bf16 MFMA GEMM, 2 streams via blockIdx.z, XOR-swizzled LDS ----------
// epi 1: fp32 C += acc (residual pre-stored); epi 2: bf16 softplus(acc+bias); epi 3: bf16 store
__global__ __launch_bounds__(256) void gemm_mfma(
    const unsigned short* __restrict__ A0, const unsigned short* __restrict__ A1,
    const unsigned short* __restrict__ Bt0, const unsigned short* __restrict__ Bt1,
    void* __restrict__ C0, void* __restrict__ C1, int ldc, int K, int epi,
    const float* __restrict__ bias0, const float* __restrict__ bias1)
{
    const unsigned short* A = blockIdx.z ? A1 : A0;
    const unsigned short* Bt = blockIdx.z ? Bt1 : Bt0;
    void* C = blockIdx.z ? C1 : C0;
    const float* bias = blockIdx.z ? bias1 : bias0;

    __shared__ unsigned short As[128 * 32];
    __shared__ unsigned short Bs[128 * 32];
    const int tid = threadIdx.x;
    const int wave = tid >> 6, lane = tid & 63;
    const int row0 = blockIdx.y * 128, col0 = blockIdx.x * 128;
    const int wm = (wave >> 1) * 64, wn = (wave & 1) * 64;
    f32x4 acc[4][4] = {};
    const int lr = lane >> 2;                                // staging row within 16
    const int gi = ((lane & 3) ^ ((lane >> 3) & 3)) * 8;     // swizzled global k-chunk
    const int fr = lane & 15, fc = lane >> 4;                // fragment row / k-chunk

    for (int k0 = 0; k0 < K; k0 += 32) {
#pragma unroll
        for (int h = 0; h < 2; h++) {
            int rb = wave * 32 + h * 16;
            const unsigned short* ga = A + (size_t)(row0 + rb + lr) * K + k0 + gi;
            const unsigned short* gb = Bt + (size_t)(col0 + rb + lr) * K + k0 + gi;
            llds16(ga, &As[rb * 32]);
            llds16(gb, &Bs[rb * 32]);
        }
        __syncthreads();
        bf16x8 af[4], bfr[4];
#pragma unroll
        for (int i = 0; i < 4; i++) {
            int r = wm + i * 16 + fr;
            af[i] = *(const bf16x8*)&As[r * 32 + (fc ^ ((r >> 1) & 3)) * 8];
        }
#pragma unroll
        for (int j = 0; j < 4; j++) {
            int r = wn + j * 16 + fr;
            bfr[j] = *(const bf16x8*)&Bs[r * 32 + (fc ^ ((r >> 1) & 3)) * 8];
        }
#pragma unroll
        for (int i = 0; i < 4; i++)
#pragma unroll
            for (int j = 0; j < 4; j++)
                acc[i][j] = __builtin_amdgcn_mfma_f32_16x16x32_bf16(af[i], bfr[j], acc[i][j], 0, 0, 0);
        __syncthreads();
    }

    const int cr = (lane >> 4) * 4, cc = lane & 15;
#pragma unroll
    for (int i = 0; i < 4; i++)
#pragma unroll
        for (int j = 0; j < 4; j++) {
            int col = col0 + wn + j * 16 + cc;
#pragma unroll
            for (int r = 0; r < 4; r++) {
                int row = row0 + wm + i * 16 + cr + r;
                size_t o = (size_t)row * ldc + col;
                float v = acc[i][j][r];
                if (epi == 1) {
                    float* Cf = (float*)C;
                    Cf[o] = v + Cf[o];
                } else if (epi == 2) {
                    v += bias[col];
                    v = (v > 20.f) ? v : log1pf(__expf(v));
                    ((unsigned short*)C)[o] = f2bf(v);
                } else {
                    ((unsigned short*)C)[o] = f2bf(v);
                }
            }
        }
}

// ---------- depthwise causal conv (K=4) + SiLU; vectorized: 8 d's/thread, taps as bf16x8 loads ----------
__global__ __launch_bounds__(256) void conv_silu_kernel(
    const unsigned short* __restrict__ uzb0, const unsigned short* __restrict__ uzb1,
    const float* __restrict__ w0, const float* __restrict__ bc0,
    const float* __restrict__ w1, const float* __restrict__ bc1,
    unsigned short* __restrict__ ub0, unsigned short* __restrict__ ub1)
{
    int s = blockIdx.y;
    const unsigned short* uzb = s ? uzb1 : uzb0;
    const float* w = s ? w1 : w0;
    const float* bc = s ? bc1 : bc0;
    unsigned short* ub = s ? ub1 : ub0;
    int idx = blockIdx.x * 256 + threadIdx.x;  // over M*CDIM/8
    int d8 = (idx % 96) * 8;
    int bl = idx / 96;
    int l = bl & (LDIM - 1);

    // weights: 32 contiguous floats starting at w[d8*4]; cached in L1/L2
    float wr[8][4];
#pragma unroll
    for (int q = 0; q < 8; q++) {
        f32x4 wv = *(const f32x4*)&w[(d8 + q) * 4];
#pragma unroll
        for (int k = 0; k < 4; k++) wr[q][k] = wv[k];
    }
    float acc[8];
    f32x4 b0 = *(const f32x4*)&bc[d8];
    f32x4 b1 = *(const f32x4*)&bc[d8 + 4];
#pragma unroll
    for (int q = 0; q < 4; q++) { acc[q] = b0[q]; acc[4 + q] = b1[q]; }

#pragma unroll
    for (int k = 0; k < 4; k++) {
        int ls = l - 3 + k;
        if (ls >= 0) {
            bf16x8 uv = *(const bf16x8*)&uzb[(size_t)(bl - 3 + k) * (2 * CDIM) + d8];
#pragma unroll
            for (int q = 0; q < 8; q++)
                acc[q] += bf2f((unsigned short)uv[q]) * wr[q][k];
        }
    }
    bf16x8 ov;
#pragma unroll
    for (int q = 0; q < 8; q++) {
        float v = acc[q];
        ov[q] = (short)f2bf(v * sigmoidf_(v));
    }
    *(bf16x8*)&ub[(size_t)bl * CDIM + d8] = ov;
}

// ---------- B/C projection GEMV: dbl(M,8) = u @ Wxp[:, 48:56] ----------
__global__ __launch_bounds__(256) void bc_gemv(
    const unsigned short* __restrict__ ub0, const unsigned short* __restrict__ ub1,
    const float* __restrict__ Wxp0, const float* __restrict__ Wxp1,
    float* __restrict__ dbl0, float* __restrict__ dbl1)
{
    int s = blockIdx.y;
    const unsigned short* ub = s ? ub1 : ub0;
    const float* Wxp = s ? Wxp1 : Wxp0;
    float* dbl = s ? dbl1 : dbl0;
    __shared__ float Wl[CDIM][8];
    int t = threadIdx.x;
    for (int i = t; i < CDIM * 8; i += 256) {
        int k = i >> 3, c = i & 7;
        Wl[k][c] = Wxp[k * 56 + RNK + c];
    }
    __syncthreads();
    int c = t & 7;
    int row = blockIdx.x * 32 + (t >> 3);
    const unsigned short* up = ub + (size_t)row * CDIM;
    float acc = 0.f;
    for (int k = 0; k < CDIM; k += 8) {
        bf16x8 uv = *(const bf16x8*)&up[k];
#pragma unroll
        for (int j = 0; j < 8; j++)
            acc += bf2f((unsigned short)uv[j]) * Wl[k + j][c];
    }
    dbl[(size_t)row * 8 + c] = acc;
}

// ---------- chunked selective scan; u/dt/z all bf16 ----------
__global__ __launch_bounds__(256) void scan_phaseA(
    const unsigned short* __restrict__ u0, const unsigned short* __restrict__ dt0,
    const float* __restrict__ dbl0, const float* __restrict__ Alog0,
    const unsigned short* __restrict__ u1, const unsigned short* __restrict__ dt1,
    const float* __restrict__ dbl1, const float* __restrict__ Alog1,
    float* __restrict__ agg)
{
    int idx = blockIdx.x * 256 + threadIdx.x;
    int d = idx % CDIM;
    int t1 = idx / CDIM;
    int c = t1 % CH;
    int t2 = t1 / CH;
    int b = t2 & 1;
    int s = t2 >> 1;
    const unsigned short* u = s ? u1 : u0;
    const unsigned short* dt = s ? dt1 : dt0;
    const float* dbl = s ? dbl1 : dbl0;
    const float* Alog = s ? Alog1 : Alog0;
    float A[4];
#pragma unroll
    for (int n = 0; n < 4; n++) A[n] = -__expf(Alog[d * 4 + n]);
    float h[4] = {0, 0, 0, 0}, aa[4] = {1, 1, 1, 1};
    int rowb = b * LDIM + c * LC;
    for (int t = 0; t < LC; t++) {
        int row = rowb + t;
        float dtv = bf2f(dt[(size_t)row * CDIM + d]);
        float uv = bf2f(u[(size_t)row * CDIM + d]);
        float du = dtv * uv;
        const float* bm = dbl + (size_t)row * 8;
#pragma unroll
        for (int n = 0; n < 4; n++) {
            float dA = __expf(dtv * A[n]);
            h[n] = dA * h[n] + du * bm[n];
            aa[n] *= dA;
        }
    }
    float* o = agg + (size_t)idx * 8;
#pragma unroll
    for (int n = 0; n < 4; n++) { o[n] = aa[n]; o[4 + n] = h[n]; }
}

__global__ __launch_bounds__(256) void scan_phaseB(const float* __restrict__ agg,
                                                   float* __restrict__ hinit)
{
    int idx = blockIdx.x * 256 + threadIdx.x;
    int d = idx % CDIM;
    int sb = idx / CDIM;
    float st[4] = {0, 0, 0, 0};
    for (int c = 0; c < CH; c++) {
        size_t base = ((size_t)sb * CH + c) * CDIM + d;
        const float* a = agg + base * 8;
        float* hi = hinit + base * 4;
#pragma unroll
        for (int n = 0; n < 4; n++) hi[n] = st[n];
#pragma unroll
        for (int n = 0; n < 4; n++) st[n] = a[n] * st[n] + a[4 + n];
    }
}

__global__ __launch_bounds__(256) void scan_phaseC(
    const unsigned short* __restrict__ u0, const unsigned short* __restrict__ dt0,
    const unsigned short* __restrict__ uzb0, const float* __restrict__ dbl0,
    const float* __restrict__ Alog0, const float* __restrict__ Dsk0, unsigned short* __restrict__ g0,
    const unsigned short* __restrict__ u1, const unsigned short* __restrict__ dt1,
    const unsigned short* __restrict__ uzb1, const float* __restrict__ dbl1,
    const float* __restrict__ Alog1, const float* __restrict__ Dsk1, unsigned short* __restrict__ g1,
    const float* __restrict__ hinit)
{
    int idx = blockIdx.x * 256 + threadIdx.x;
    int d = idx % CDIM;
    int t1 = idx / CDIM;
    int c = t1 % CH;
    int t2 = t1 / CH;
    int b = t2 & 1;
    int s = t2 >> 1;
    const unsigned short* u = s ? u1 : u0;
    const unsigned short* dt = s ? dt1 : dt0;
    const unsigned short* uzb = s ? uzb1 : uzb0;
    const float* dbl = s ? dbl1 : dbl0;
    const float* dblO = s ? dbl0 : dbl1;  // cross: other stream's C projection
    const float* Alog = s ? Alog1 : Alog0;
    const float* Dsk = s ? Dsk1 : Dsk0;
    unsigned short* gated = s ? g1 : g0;
    float A[4];
#pragma unroll
    for (int n = 0; n < 4; n++) A[n] = -__expf(Alog[d * 4 + n]);
    float Dv = Dsk[d];
    float h[4];
    const float* hi = hinit + (size_t)idx * 4;
#pragma unroll
    for (int n = 0; n < 4; n++) h[n] = hi[n];
    int rowb = b * LDIM + c * LC;
    for (int t = 0; t < LC; t++) {
        int row = rowb + t;
        float dtv = bf2f(dt[(size_t)row * CDIM + d]);
        float uv = bf2f(u[(size_t)row * CDIM + d]);
        float du = dtv * uv;
        const float* bm = dbl + (size_t)row * 8;
        const float* cm = dblO + (size_t)row * 8 + 4;
        float y = 0.f;
#pragma unroll
        for (int n = 0; n < 4; n++) {
            float dA = __expf(dtv * A[n]);
            h[n] = dA * h[n] + du * bm[n];
            y += h[n] * cm[n];
        }
        y += uv * Dv;
        float zv = bf2f(uzb[(size_t)row * (2 * CDIM) + CDIM + d]);
        gated[(size_t)row * CDIM + d] = f2bf(y * (zv * sigmoidf_(zv)));
    }
}

extern "C" void kernel_launch(void* const* d_in, const int* in_sizes, int n_in,
                              void* d_out, int out_size, void* d_ws, size_t ws_size,
                              hipStream_t stream)
{
    const float* x[2] = {(const float*)d_in[0], (const float*)d_in[1]};
    const float *ln_g[2], *ln_b[2], *Win[2], *Wconv[2], *bconv[2], *Wxp[2],
        *Wdt[2], *bdt[2], *Alog[2], *Dskip[2], *Wout[2];
    for (int s = 0; s < 2; s++) {
        int base = 2 + s * 11;
        ln_g[s] = (const float*)d_in[base + 0];
        ln_b[s] = (const float*)d_in[base + 1];
        Win[s] = (const float*)d_in[base + 2];
        Wconv[s] = (const float*)d_in[base + 3];
        bconv[s] = (const float*)d_in[base + 4];
        Wxp[s] = (const float*)d_in[base + 5];
        Wdt[s] = (const float*)d_in[base + 6];
        bdt[s] = (const float*)d_in[base + 7];
        Alog[s] = (const float*)d_in[base + 8];
        Dskip[s] = (const float*)d_in[base + 9];
        Wout[s] = (const float*)d_in[base + 10];
    }

    const int M = BDIM * LDIM;  // 8192
    char* base = (char*)d_ws;
    auto alloc = [&](size_t bytes) {
        char* p = base;
        base += (bytes + 255) & ~(size_t)255;
        return p;
    };
    unsigned short* uzb[2] = {(unsigned short*)alloc((size_t)M * 1536 * 2),
                              (unsigned short*)alloc((size_t)M * 1536 * 2)};
    unsigned short* dtb[2] = {(unsigned short*)alloc((size_t)M * CDIM * 2),
                              (unsigned short*)alloc((size_t)M * CDIM * 2)};
    unsigned short* ub[2] = {(unsigned short*)alloc((size_t)M * CDIM * 2),
                             (unsigned short*)alloc((size_t)M * CDIM * 2)};
    unsigned short* xnb[2] = {(unsigned short*)alloc((size_t)M * CDIM * 2),
                              (unsigned short*)alloc((size_t)M * CDIM * 2)};  // reused as gated
    float* dbl[2] = {(float*)alloc((size_t)M * 8 * 4), (float*)alloc((size_t)M * 8 * 4)};
    unsigned short* WinT[2] = {(unsigned short*)alloc(1536 * 768 * 2),
                               (unsigned short*)alloc(1536 * 768 * 2)};
    unsigned short* WoutT[2] = {(unsigned short*)alloc(768 * 768 * 2),
                                (unsigned short*)alloc(768 * 768 * 2)};
    unsigned short* WcombT[2] = {(unsigned short*)alloc(768 * 768 * 2),
                                 (unsigned short*)alloc(768 * 768 * 2)};
    float* agg = (float*)alloc((size_t)2 * BDIM * CH * CDIM * 8 * 4);
    float* hinit = (float*)alloc((size_t)2 * BDIM * CH * CDIM * 4 * 4);
    float* stats = (float*)alloc((size_t)2 * M * 2 * 4);

    dim3 blk(256);
    const size_t SZ = (size_t)BDIM * LDIM * CDIM;

    // LN stats + transpose (pre-stores residual into d_out)
    stats_kernel<<<dim3(256), blk, 0, stream>>>(x[0], x[1], stats);
    transpose_ln_kernel<<<dim3(CDIM / 64, LDIM / 64, 4), blk, 0, stream>>>(
        x[0], x[1], ln_g[0], ln_b[0], ln_g[1], ln_b[1], stats, xnb[0], xnb[1], (float*)d_out);

    // weight prep
    for (int s = 0; s < 2; s++) {
        wt_transpose<<<dim3(1536 / 64, 768 / 64), blk, 0, stream>>>(Win[s], WinT[s], CDIM, 2 * CDIM);
        wt_transpose<<<dim3(768 / 64, 768 / 64), blk, 0, stream>>>(Wout[s], WoutT[s], CDIM, CDIM);
        wcomb_kernel<<<dim3(768 / 64, 768 / 64), blk, 0, stream>>>(Wxp[s], Wdt[s], WcombT[s]);
    }

    // in_proj (both streams): bf16 MFMA -> uzb bf16 (M,1536)
    gemm_mfma<<<dim3(1536 / 128, M / 128, 2), blk, 0, stream>>>(
        xnb[0], xnb[1], WinT[0], WinT[1], uzb[0], uzb[1], 2 * CDIM, CDIM, 3, nullptr, nullptr);

    // depthwise conv + SiLU (both streams) -> ub bf16
    conv_silu_kernel<<<dim3((M * CDIM / 8) / 256, 2), blk, 0, stream>>>(
        uzb[0], uzb[1], Wconv[0], bconv[0], Wconv[1], bconv[1], ub[0], ub[1]);

    // dt = softplus(u @ Wcomb + bdt) -> dtb bf16 (both streams)
    gemm_mfma<<<dim3(CDIM / 128, M / 128, 2), blk, 0, stream>>>(
        ub[0], ub[1], WcombT[0], WcombT[1], dtb[0], dtb[1], CDIM, CDIM, 2, bdt[0], bdt[1]);

    // B/C projection for both streams
    bc_gemv<<<dim3(M / 32, 2), blk, 0, stream>>>(ub[0], ub[1], Wxp[0], Wxp[1], dbl[0], dbl[1]);

    // cross selective scan (3 phases); gating fused, writes bf16 gated into xnb
    scan_phaseA<<<dim3((2 * BDIM * CH * CDIM) / 256), blk, 0, stream>>>(
        ub[0], dtb[0], dbl[0], Alog[0], ub[1], dtb[1], dbl[1], Alog[1], agg);
    scan_phaseB<<<dim3((2 * BDIM * CDIM) / 256), blk, 0, stream>>>(agg, hinit);
    scan_phaseC<<<dim3((2 * BDIM * CH * CDIM) / 256), blk, 0, stream>>>(
        ub[0], dtb[0], uzb[0], dbl[0], Alog[0], Dskip[0], xnb[0],
        ub[1], dtb[1], uzb[1], dbl[1], Alog[1], Dskip[1], xnb[1], hinit);

    // out_proj (both streams): bf16 MFMA, adds into pre-stored residual in d_out
    float* out = (float*)d_out;
    gemm_mfma<<<dim3(CDIM / 128, M / 128, 2), blk, 0, stream>>>(
        xnb[0], xnb[1], WoutT[0], WoutT[1], out, out + SZ, CDIM, CDIM, 1, nullptr, nullptr);
}

// Round 6
// 543.510 us; speedup vs baseline: 3.2226x; 1.1134x over previous
//
#include <hip/hip_runtime.h>
#include <cmath>

#define LDIM 4096
#define CDIM 768
#define BDIM 2
#define NST 4
#define RNK 48
#define CH 64     // scan chunks per sequence
#define LC 64     // chunk length (CH*LC == LDIM)

typedef short bf16x8 __attribute__((ext_vector_type(8)));
typedef float f32x4 __attribute__((ext_vector_type(4)));

__device__ __forceinline__ float sigmoidf_(float x) { return 1.f / (1.f + __expf(-x)); }

__device__ __forceinline__ unsigned short f2bf(float f) {
    unsigned int u = __float_as_uint(f);
    u += 0x7fffu + ((u >> 16) & 1u);
    return (unsigned short)(u >> 16);
}
__device__ __forceinline__ float bf2f(unsigned short us) {
    unsigned int u = ((unsigned int)us) << 16;
    return __uint_as_float(u);
}

__device__ __forceinline__ void llds16(const unsigned short* g, unsigned short* l) {
    __builtin_amdgcn_global_load_lds(
        (const __attribute__((address_space(1))) unsigned int*)g,
        (__attribute__((address_space(3))) unsigned int*)l, 16, 0, 0);
}

// ---------- LN stats: 256 blocks, 4 waves split C, deep-unrolled loads, LDS reduce ----------
__global__ __launch_bounds__(256) void stats_kernel(const float* __restrict__ x0,
                                                    const float* __restrict__ x1,
                                                    float* __restrict__ stats)
{
    int blk = blockIdx.x;  // 0..255: s(1) b(1) lgroup(6)
    int s = blk >> 7;
    int b = (blk >> 6) & 1;
    int l0 = (blk & 63) * 64;
    int wave = threadIdx.x >> 6, lane = threadIdx.x & 63;
    const float* x = s ? x1 : x0;
    const float* xp = x + ((size_t)b * CDIM) * LDIM + l0 + lane;
    float sm = 0.f, sq = 0.f;
    int cbeg = wave * 192;
#pragma unroll
    for (int i0 = 0; i0 < 192; i0 += 16) {
        float v[16];
#pragma unroll
        for (int j = 0; j < 16; j++) v[j] = xp[(size_t)(cbeg + i0 + j) * LDIM];
#pragma unroll
        for (int j = 0; j < 16; j++) { sm += v[j]; sq += v[j] * v[j]; }
    }
    __shared__ float red[2][4][64];
    red[0][wave][lane] = sm;
    red[1][wave][lane] = sq;
    __syncthreads();
    if (wave == 0) {
        float s_ = red[0][0][lane] + red[0][1][lane] + red[0][2][lane] + red[0][3][lane];
        float q_ = red[1][0][lane] + red[1][1][lane] + red[1][2][lane] + red[1][3][lane];
        float m = s_ * (1.f / CDIM);
        float var = q_ * (1.f / CDIM) - m * m;
        int idx = s * 8192 + b * LDIM + l0 + lane;
        stats[2 * idx] = m;
        stats[2 * idx + 1] = rsqrtf(var + 1e-5f);
    }
}

// ---------- transpose + LN: x (B,C,L) -> xn bf16 (B*L, C); raw x -> d_out (residual pre-store) ----------
__global__ __launch_bounds__(256) void transpose_ln_kernel(
    const float* __restrict__ x0, const float* __restrict__ x1,
    const float* __restrict__ g0, const float* __restrict__ bb0,
    const float* __restrict__ g1, const float* __restrict__ bb1,
    const float* __restrict__ stats,
    unsigned short* __restrict__ xnb0, unsigned short* __restrict__ xnb1,
    float* __restrict__ out)
{
    __shared__ float tile[64][65];
    int t = threadIdx.x;
    int c0 = blockIdx.x * 64, l0 = blockIdx.y * 64;
    int z = blockIdx.z;
    int s = z >> 1, b = z & 1;
    const float* x = s ? x1 : x0;
    const float* g = s ? g1 : g0;
    const float* bb = s ? bb1 : bb0;
    unsigned short* xnb = s ? xnb1 : xnb0;
    int tl = t & 63, tg = t >> 6;
#pragma unroll
    for (int i = 0; i < 16; i++) {
        int cl = tg * 16 + i;
        tile[cl][tl] = x[((size_t)(b * CDIM + c0 + cl)) * LDIM + l0 + tl];
    }
    __syncthreads();
    const size_t SZ = (size_t)BDIM * LDIM * CDIM;
#pragma unroll
    for (int i = 0; i < 16; i++) {
        int ll = tg * 16 + i;
        int l = l0 + ll, c = c0 + tl;
        float v = tile[tl][ll];
        int sidx = s * 8192 + b * LDIM + l;
        float m = stats[sidx * 2], rs = stats[sidx * 2 + 1];
        size_t o = ((size_t)(b * LDIM + l)) * CDIM + c;
        out[(size_t)s * SZ + o] = v;  // residual pre-store
        xnb[o] = f2bf((v - m) * rs * g[c] + bb[c]);
    }
}

// ---------- weight transpose/convert: W (K,N) fp32 -> Wt (N,K) bf16 ----------
__global__ __launch_bounds__(256) void wt_transpose(const float* __restrict__ W,
                                                    unsigned short* __restrict__ Wt,
                                                    int K, int N)
{
    __shared__ float tile[64][65];
    int t = threadIdx.x;
    int n0 = blockIdx.x * 64, k0 = blockIdx.y * 64;
    int tn = t & 63, tg = t >> 6;
#pragma unroll
    for (int i = 0; i < 16; i++) {
        int kl = tg * 16 + i;
        tile[kl][tn] = W[(size_t)(k0 + kl) * N + n0 + tn];
    }
    __syncthreads();
#pragma unroll
    for (int i = 0; i < 16; i++) {
        int nl = tg * 16 + i;
        int k = k0 + tn, n = n0 + nl;
        Wt[(size_t)n * K + k] = f2bf(tile[tn][nl]);
    }
}

// ---------- Wcomb = Wxp[:, :48] @ Wdt  -> WcombT (N=768, K=768) bf16 ----------
__global__ __launch_bounds__(256) void wcomb_kernel(const float* __restrict__ Wxp,
                                                    const float* __restrict__ Wdt,
                                                    unsigned short* __restrict__ WcombT)
{
    int t = threadIdx.x;
    int k = blockIdx.x * 64 + (t & 63);
    int n0 = blockIdx.y * 64;
    float wx[RNK];
#pragma unroll
    for (int r = 0; r < RNK; r++) wx[r] = Wxp[k * 56 + r];
    for (int i = (t >> 6); i < 64; i += 4) {
        int n = n0 + i;
        float acc = 0.f;
#pragma unroll
        for (int r = 0; r < RNK; r++) acc += wx[r] * Wdt[(size_t)r * CDIM + n];
        WcombT[(size_t)n * CDIM + k] = f2bf(acc);
    }
}

// ---------- bf16 MFMA GEMM, 2 streams via blockIdx.z, XOR-swizzled LDS ----------
// Grid: x = ROW tile, y = COL tile (same-row blocks land on same XCD: bids differ by
// gridDim.x=64 === 0 mod 8 -> A row-tile stays in one XCD's L2).
// epi 1: fp32 C += acc (residual pre-stored); epi 2: bf16 softplus(acc+bias); epi 3: bf16 store
__global__ __launch_bounds__(256) void gemm_mfma(
    const unsigned short* __restrict__ A0, const unsigned short* __restrict__ A1,
    const unsigned short* __restrict__ Bt0, const unsigned short* __restrict__ Bt1,
    void* __restrict__ C0, void* __restrict__ C1, int ldc, int K, int epi,
    const float* __restrict__ bias0, const float* __restrict__ bias1)
{
    const unsigned short* A = blockIdx.z ? A1 : A0;
    const unsigned short* Bt = blockIdx.z ? Bt1 : Bt0;
    void* C = blockIdx.z ? C1 : C0;
    const float* bias = blockIdx.z ? bias1 : bias0;

    __shared__ unsigned short As[128 * 32];
    __shared__ unsigned short Bs[128 * 32];
    const int tid = threadIdx.x;
    const int wave = tid >> 6, lane = tid & 63;
    const int row0 = blockIdx.x * 128, col0 = blockIdx.y * 128;
    const int wm = (wave >> 1) * 64, wn = (wave & 1) * 64;
    f32x4 acc[4][4] = {};
    const int lr = lane >> 2;                                // staging row within 16
    const int gi = ((lane & 3) ^ ((lane >> 3) & 3)) * 8;     // swizzled global k-chunk
    const int fr = lane & 15, fc = lane >> 4;                // fragment row / k-chunk

    for (int k0 = 0; k0 < K; k0 += 32) {
#pragma unroll
        for (int h = 0; h < 2; h++) {
            int rb = wave * 32 + h * 16;
            const unsigned short* ga = A + (size_t)(row0 + rb + lr) * K + k0 + gi;
            const unsigned short* gb = Bt + (size_t)(col0 + rb + lr) * K + k0 + gi;
            llds16(ga, &As[rb * 32]);
            llds16(gb, &Bs[rb * 32]);
        }
        __syncthreads();
        bf16x8 af[4], bfr[4];
#pragma unroll
        for (int i = 0; i < 4; i++) {
            int r = wm + i * 16 + fr;
            af[i] = *(const bf16x8*)&As[r * 32 + (fc ^ ((r >> 1) & 3)) * 8];
        }
#pragma unroll
        for (int j = 0; j < 4; j++) {
            int r = wn + j * 16 + fr;
            bfr[j] = *(const bf16x8*)&Bs[r * 32 + (fc ^ ((r >> 1) & 3)) * 8];
        }
#pragma unroll
        for (int i = 0; i < 4; i++)
#pragma unroll
            for (int j = 0; j < 4; j++)
                acc[i][j] = __builtin_amdgcn_mfma_f32_16x16x32_bf16(af[i], bfr[j], acc[i][j], 0, 0, 0);
        __syncthreads();
    }

    const int cr = (lane >> 4) * 4, cc = lane & 15;
#pragma unroll
    for (int i = 0; i < 4; i++)
#pragma unroll
        for (int j = 0; j < 4; j++) {
            int col = col0 + wn + j * 16 + cc;
#pragma unroll
            for (int r = 0; r < 4; r++) {
                int row = row0 + wm + i * 16 + cr + r;
                size_t o = (size_t)row * ldc + col;
                float v = acc[i][j][r];
                if (epi == 1) {
                    float* Cf = (float*)C;
                    Cf[o] = v + Cf[o];
                } else if (epi == 2) {
                    v += bias[col];
                    v = (v > 20.f) ? v : __logf(1.f + __expf(v));
                    ((unsigned short*)C)[o] = f2bf(v);
                } else {
                    ((unsigned short*)C)[o] = f2bf(v);
                }
            }
        }
}

// ---------- depthwise causal conv (K=4) + SiLU; vectorized: 8 d's/thread, taps as bf16x8 loads ----------
__global__ __launch_bounds__(256) void conv_silu_kernel(
    const unsigned short* __restrict__ uzb0, const unsigned short* __restrict__ uzb1,
    const float* __restrict__ w0, const float* __restrict__ bc0,
    const float* __restrict__ w1, const float* __restrict__ bc1,
    unsigned short* __restrict__ ub0, unsigned short* __restrict__ ub1)
{
    int s = blockIdx.y;
    const unsigned short* uzb = s ? uzb1 : uzb0;
    const float* w = s ? w1 : w0;
    const float* bc = s ? bc1 : bc0;
    unsigned short* ub = s ? ub1 : ub0;
    int idx = blockIdx.x * 256 + threadIdx.x;  // over M*CDIM/8
    int d8 = (idx % 96) * 8;
    int bl = idx / 96;
    int l = bl & (LDIM - 1);

    float wr[8][4];
#pragma unroll
    for (int q = 0; q < 8; q++) {
        f32x4 wv = *(const f32x4*)&w[(d8 + q) * 4];
#pragma unroll
        for (int k = 0; k < 4; k++) wr[q][k] = wv[k];
    }
    float acc[8];
    f32x4 b0 = *(const f32x4*)&bc[d8];
    f32x4 b1 = *(const f32x4*)&bc[d8 + 4];
#pragma unroll
    for (int q = 0; q < 4; q++) { acc[q] = b0[q]; acc[4 + q] = b1[q]; }

#pragma unroll
    for (int k = 0; k < 4; k++) {
        int ls = l - 3 + k;
        if (ls >= 0) {
            bf16x8 uv = *(const bf16x8*)&uzb[(size_t)(bl - 3 + k) * (2 * CDIM) + d8];
#pragma unroll
            for (int q = 0; q < 8; q++)
                acc[q] += bf2f((unsigned short)uv[q]) * wr[q][k];
        }
    }
    bf16x8 ov;
#pragma unroll
    for (int q = 0; q < 8; q++) {
        float v = acc[q];
        ov[q] = (short)f2bf(v * sigmoidf_(v));
    }
    *(bf16x8*)&ub[(size_t)bl * CDIM + d8] = ov;
}

// ---------- B/C projection GEMV: dbl(M,8) = u @ Wxp[:, 48:56] ----------
__global__ __launch_bounds__(256) void bc_gemv(
    const unsigned short* __restrict__ ub0, const unsigned short* __restrict__ ub1,
    const float* __restrict__ Wxp0, const float* __restrict__ Wxp1,
    float* __restrict__ dbl0, float* __restrict__ dbl1)
{
    int s = blockIdx.y;
    const unsigned short* ub = s ? ub1 : ub0;
    const float* Wxp = s ? Wxp1 : Wxp0;
    float* dbl = s ? dbl1 : dbl0;
    __shared__ float Wl[CDIM][8];
    int t = threadIdx.x;
    for (int i = t; i < CDIM * 8; i += 256) {
        int k = i >> 3, c = i & 7;
        Wl[k][c] = Wxp[k * 56 + RNK + c];
    }
    __syncthreads();
    int c = t & 7;
    int row = blockIdx.x * 32 + (t >> 3);
    const unsigned short* up = ub + (size_t)row * CDIM;
    float acc = 0.f;
    for (int k = 0; k < CDIM; k += 8) {
        bf16x8 uv = *(const bf16x8*)&up[k];
#pragma unroll
        for (int j = 0; j < 8; j++)
            acc += bf2f((unsigned short)uv[j]) * Wl[k + j][c];
    }
    dbl[(size_t)row * 8 + c] = acc;
}

// ---------- chunked selective scan; u/dt/z all bf16 ----------
__global__ __launch_bounds__(256) void scan_phaseA(
    const unsigned short* __restrict__ u0, const unsigned short* __restrict__ dt0,
    const float* __restrict__ dbl0, const float* __restrict__ Alog0,
    const unsigned short* __restrict__ u1, const unsigned short* __restrict__ dt1,
    const float* __restrict__ dbl1, const float* __restrict__ Alog1,
    float* __restrict__ agg)
{
    int idx = blockIdx.x * 256 + threadIdx.x;
    int d = idx % CDIM;
    int t1 = idx / CDIM;
    int c = t1 % CH;
    int t2 = t1 / CH;
    int b = t2 & 1;
    int s = t2 >> 1;
    const unsigned short* u = s ? u1 : u0;
    const unsigned short* dt = s ? dt1 : dt0;
    const float* dbl = s ? dbl1 : dbl0;
    const float* Alog = s ? Alog1 : Alog0;
    float A[4];
#pragma unroll
    for (int n = 0; n < 4; n++) A[n] = -__expf(Alog[d * 4 + n]);
    float h[4] = {0, 0, 0, 0}, aa[4] = {1, 1, 1, 1};
    int rowb = b * LDIM + c * LC;
    for (int t = 0; t < LC; t++) {
        int row = rowb + t;
        float dtv = bf2f(dt[(size_t)row * CDIM + d]);
        float uv = bf2f(u[(size_t)row * CDIM + d]);
        float du = dtv * uv;
        const float* bm = dbl + (size_t)row * 8;
#pragma unroll
        for (int n = 0; n < 4; n++) {
            float dA = __expf(dtv * A[n]);
            h[n] = dA * h[n] + du * bm[n];
            aa[n] *= dA;
        }
    }
    float* o = agg + (size_t)idx * 8;
#pragma unroll
    for (int n = 0; n < 4; n++) { o[n] = aa[n]; o[4 + n] = h[n]; }
}

__global__ __launch_bounds__(256) void scan_phaseB(const float* __restrict__ agg,
                                                   float* __restrict__ hinit)
{
    int idx = blockIdx.x * 256 + threadIdx.x;
    int d = idx % CDIM;
    int sb = idx / CDIM;
    float st[4] = {0, 0, 0, 0};
    for (int c = 0; c < CH; c++) {
        size_t base = ((size_t)sb * CH + c) * CDIM + d;
        const float* a = agg + base * 8;
        float* hi = hinit + base * 4;
#pragma unroll
        for (int n = 0; n < 4; n++) hi[n] = st[n];
#pragma unroll
        for (int n = 0; n < 4; n++) st[n] = a[n] * st[n] + a[4 + n];
    }
}

__global__ __launch_bounds__(256) void scan_phaseC(
    const unsigned short* __restrict__ u0, const unsigned short* __restrict__ dt0,
    const unsigned short* __restrict__ uzb0, const float* __restrict__ dbl0,
    const float* __restrict__ Alog0, const float* __restrict__ Dsk0, unsigned short* __restrict__ g0,
    const unsigned short* __restrict__ u1, const unsigned short* __restrict__ dt1,
    const unsigned short* __restrict__ uzb1, const float* __restrict__ dbl1,
    const float* __restrict__ Alog1, const float* __restrict__ Dsk1, unsigned short* __restrict__ g1,
    const float* __restrict__ hinit)
{
    int idx = blockIdx.x * 256 + threadIdx.x;
    int d = idx % CDIM;
    int t1 = idx / CDIM;
    int c = t1 % CH;
    int t2 = t1 / CH;
    int b = t2 & 1;
    int s = t2 >> 1;
    const unsigned short* u = s ? u1 : u0;
    const unsigned short* dt = s ? dt1 : dt0;
    const unsigned short* uzb = s ? uzb1 : uzb0;
    const float* dbl = s ? dbl1 : dbl0;
    const float* dblO = s ? dbl0 : dbl1;  // cross: other stream's C projection
    const float* Alog = s ? Alog1 : Alog0;
    const float* Dsk = s ? Dsk1 : Dsk0;
    unsigned short* gated = s ? g1 : g0;
    float A[4];
#pragma unroll
    for (int n = 0; n < 4; n++) A[n] = -__expf(Alog[d * 4 + n]);
    float Dv = Dsk[d];
    float h[4];
    const float* hi = hinit + (size_t)idx * 4;
#pragma unroll
    for (int n = 0; n < 4; n++) h[n] = hi[n];
    int rowb = b * LDIM + c * LC;
    for (int t = 0; t < LC; t++) {
        int row = rowb + t;
        float dtv = bf2f(dt[(size_t)row * CDIM + d]);
        float uv = bf2f(u[(size_t)row * CDIM + d]);
        float du = dtv * uv;
        const float* bm = dbl + (size_t)row * 8;
        const float* cm = dblO + (size_t)row * 8 + 4;
        float y = 0.f;
#pragma unroll
        for (int n = 0; n < 4; n++) {
            float dA = __expf(dtv * A[n]);
            h[n] = dA * h[n] + du * bm[n];
            y += h[n] * cm[n];
        }
        y += uv * Dv;
        float zv = bf2f(uzb[(size_t)row * (2 * CDIM) + CDIM + d]);
        gated[(size_t)row * CDIM + d] = f2bf(y * (zv * sigmoidf_(zv)));
    }
}

extern "C" void kernel_launch(void* const* d_in, const int* in_sizes, int n_in,
                              void* d_out, int out_size, void* d_ws, size_t ws_size,
                              hipStream_t stream)
{
    const float* x[2] = {(const float*)d_in[0], (const float*)d_in[1]};
    const float *ln_g[2], *ln_b[2], *Win[2], *Wconv[2], *bconv[2], *Wxp[2],
        *Wdt[2], *bdt[2], *Alog[2], *Dskip[2], *Wout[2];
    for (int s = 0; s < 2; s++) {
        int base = 2 + s * 11;
        ln_g[s] = (const float*)d_in[base + 0];
        ln_b[s] = (const float*)d_in[base + 1];
        Win[s] = (const float*)d_in[base + 2];
        Wconv[s] = (const float*)d_in[base + 3];
        bconv[s] = (const float*)d_in[base + 4];
        Wxp[s] = (const float*)d_in[base + 5];
        Wdt[s] = (const float*)d_in[base + 6];
        bdt[s] = (const float*)d_in[base + 7];
        Alog[s] = (const float*)d_in[base + 8];
        Dskip[s] = (const float*)d_in[base + 9];
        Wout[s] = (const float*)d_in[base + 10];
    }

    const int M = BDIM * LDIM;  // 8192
    char* base = (char*)d_ws;
    auto alloc = [&](size_t bytes) {
        char* p = base;
        base += (bytes + 255) & ~(size_t)255;
        return p;
    };
    unsigned short* uzb[2] = {(unsigned short*)alloc((size_t)M * 1536 * 2),
                              (unsigned short*)alloc((size_t)M * 1536 * 2)};
    unsigned short* dtb[2] = {(unsigned short*)alloc((size_t)M * CDIM * 2),
                              (unsigned short*)alloc((size_t)M * CDIM * 2)};
    unsigned short* ub[2] = {(unsigned short*)alloc((size_t)M * CDIM * 2),
                             (unsigned short*)alloc((size_t)M * CDIM * 2)};
    unsigned short* xnb[2] = {(unsigned short*)alloc((size_t)M * CDIM * 2),
                              (unsigned short*)alloc((size_t)M * CDIM * 2)};  // reused as gated
    float* dbl[2] = {(float*)alloc((size_t)M * 8 * 4), (float*)alloc((size_t)M * 8 * 4)};
    unsigned short* WinT[2] = {(unsigned short*)alloc(1536 * 768 * 2),
                               (unsigned short*)alloc(1536 * 768 * 2)};
    unsigned short* WoutT[2] = {(unsigned short*)alloc(768 * 768 * 2),
                                (unsigned short*)alloc(768 * 768 * 2)};
    unsigned short* WcombT[2] = {(unsigned short*)alloc(768 * 768 * 2),
                                 (unsigned short*)alloc(768 * 768 * 2)};
    float* agg = (float*)alloc((size_t)2 * BDIM * CH * CDIM * 8 * 4);
    float* hinit = (float*)alloc((size_t)2 * BDIM * CH * CDIM * 4 * 4);
    float* stats = (float*)alloc((size_t)2 * M * 2 * 4);

    dim3 blk(256);
    const size_t SZ = (size_t)BDIM * LDIM * CDIM;

    // LN stats + transpose (pre-stores residual into d_out)
    stats_kernel<<<dim3(256), blk, 0, stream>>>(x[0], x[1], stats);
    transpose_ln_kernel<<<dim3(CDIM / 64, LDIM / 64, 4), blk, 0, stream>>>(
        x[0], x[1], ln_g[0], ln_b[0], ln_g[1], ln_b[1], stats, xnb[0], xnb[1], (float*)d_out);

    // weight prep
    for (int s = 0; s < 2; s++) {
        wt_transpose<<<dim3(1536 / 64, 768 / 64), blk, 0, stream>>>(Win[s], WinT[s], CDIM, 2 * CDIM);
        wt_transpose<<<dim3(768 / 64, 768 / 64), blk, 0, stream>>>(Wout[s], WoutT[s], CDIM, CDIM);
        wcomb_kernel<<<dim3(768 / 64, 768 / 64), blk, 0, stream>>>(Wxp[s], Wdt[s], WcombT[s]);
    }

    // in_proj (both streams): bf16 MFMA -> uzb bf16 (M,1536); grid x=row-tile for XCD L2 reuse
    gemm_mfma<<<dim3(M / 128, 1536 / 128, 2), blk, 0, stream>>>(
        xnb[0], xnb[1], WinT[0], WinT[1], uzb[0], uzb[1], 2 * CDIM, CDIM, 3, nullptr, nullptr);

    // depthwise conv + SiLU (both streams) -> ub bf16
    conv_silu_kernel<<<dim3((M * CDIM / 8) / 256, 2), blk, 0, stream>>>(
        uzb[0], uzb[1], Wconv[0], bconv[0], Wconv[1], bconv[1], ub[0], ub[1]);

    // dt = softplus(u @ Wcomb + bdt) -> dtb bf16 (both streams)
    gemm_mfma<<<dim3(M / 128, CDIM / 128, 2), blk, 0, stream>>>(
        ub[0], ub[1], WcombT[0], WcombT[1], dtb[0], dtb[1], CDIM, CDIM, 2, bdt[0], bdt[1]);

    // B/C projection for both streams
    bc_gemv<<<dim3(M / 32, 2), blk, 0, stream>>>(ub[0], ub[1], Wxp[0], Wxp[1], dbl[0], dbl[1]);

    // cross selective scan (3 phases); gating fused, writes bf16 gated into xnb
    scan_phaseA<<<dim3((2 * BDIM * CH * CDIM) / 256), blk, 0, stream>>>(
        ub[0], dtb[0], dbl[0], Alog[0], ub[1], dtb[1], dbl[1], Alog[1], agg);
    scan_phaseB<<<dim3((2 * BDIM * CDIM) / 256), blk, 0, stream>>>(agg, hinit);
    scan_phaseC<<<dim3((2 * BDIM * CH * CDIM) / 256), blk, 0, stream>>>(
        ub[0], dtb[0], uzb[0], dbl[0], Alog[0], Dskip[0], xnb[0],
        ub[1], dtb[1], uzb[1], dbl[1], Alog[1], Dskip[1], xnb[1], hinit);

    // out_proj (both streams): bf16 MFMA, adds into pre-stored residual in d_out
    float* out = (float*)d_out;
    gemm_mfma<<<dim3(M / 128, CDIM / 128, 2), blk, 0, stream>>>(
        xnb[0], xnb[1], WoutT[0], WoutT[1], out, out + SZ, CDIM, CDIM, 1, nullptr, nullptr);
}

// Round 7
// 537.982 us; speedup vs baseline: 3.2557x; 1.0103x over previous
//
#include <hip/hip_runtime.h>
#include <cmath>

#define LDIM 4096
#define CDIM 768
#define BDIM 2
#define NST 4
#define RNK 48
#define CH 64     // scan chunks per sequence
#define LC 64     // chunk length (CH*LC == LDIM)

typedef short bf16x8 __attribute__((ext_vector_type(8)));
typedef float f32x4 __attribute__((ext_vector_type(4)));

__device__ __forceinline__ float sigmoidf_(float x) { return 1.f / (1.f + __expf(-x)); }

__device__ __forceinline__ unsigned short f2bf(float f) {
    unsigned int u = __float_as_uint(f);
    u += 0x7fffu + ((u >> 16) & 1u);
    return (unsigned short)(u >> 16);
}
__device__ __forceinline__ float bf2f(unsigned short us) {
    unsigned int u = ((unsigned int)us) << 16;
    return __uint_as_float(u);
}

__device__ __forceinline__ void llds16(const unsigned short* g, unsigned short* l) {
    __builtin_amdgcn_global_load_lds(
        (const __attribute__((address_space(1))) unsigned int*)g,
        (__attribute__((address_space(3))) unsigned int*)l, 16, 0, 0);
}

// ---------- LN stats: 256 blocks, 4 waves split C, deep-unrolled loads, LDS reduce ----------
__global__ __launch_bounds__(256) void stats_kernel(const float* __restrict__ x0,
                                                    const float* __restrict__ x1,
                                                    float* __restrict__ stats)
{
    int blk = blockIdx.x;  // 0..255: s(1) b(1) lgroup(6)
    int s = blk >> 7;
    int b = (blk >> 6) & 1;
    int l0 = (blk & 63) * 64;
    int wave = threadIdx.x >> 6, lane = threadIdx.x & 63;
    const float* x = s ? x1 : x0;
    const float* xp = x + ((size_t)b * CDIM) * LDIM + l0 + lane;
    float sm = 0.f, sq = 0.f;
    int cbeg = wave * 192;
#pragma unroll
    for (int i0 = 0; i0 < 192; i0 += 16) {
        float v[16];
#pragma unroll
        for (int j = 0; j < 16; j++) v[j] = xp[(size_t)(cbeg + i0 + j) * LDIM];
#pragma unroll
        for (int j = 0; j < 16; j++) { sm += v[j]; sq += v[j] * v[j]; }
    }
    __shared__ float red[2][4][64];
    red[0][wave][lane] = sm;
    red[1][wave][lane] = sq;
    __syncthreads();
    if (wave == 0) {
        float s_ = red[0][0][lane] + red[0][1][lane] + red[0][2][lane] + red[0][3][lane];
        float q_ = red[1][0][lane] + red[1][1][lane] + red[1][2][lane] + red[1][3][lane];
        float m = s_ * (1.f / CDIM);
        float var = q_ * (1.f / CDIM) - m * m;
        int idx = s * 8192 + b * LDIM + l0 + lane;
        stats[2 * idx] = m;
        stats[2 * idx + 1] = rsqrtf(var + 1e-5f);
    }
}

// ---------- transpose + LN: x (B,C,L) -> xn bf16 (B*L, C); raw x -> d_out (residual pre-store) ----------
__global__ __launch_bounds__(256) void transpose_ln_kernel(
    const float* __restrict__ x0, const float* __restrict__ x1,
    const float* __restrict__ g0, const float* __restrict__ bb0,
    const float* __restrict__ g1, const float* __restrict__ bb1,
    const float* __restrict__ stats,
    unsigned short* __restrict__ xnb0, unsigned short* __restrict__ xnb1,
    float* __restrict__ out)
{
    __shared__ float tile[64][65];
    int t = threadIdx.x;
    int c0 = blockIdx.x * 64, l0 = blockIdx.y * 64;
    int z = blockIdx.z;
    int s = z >> 1, b = z & 1;
    const float* x = s ? x1 : x0;
    const float* g = s ? g1 : g0;
    const float* bb = s ? bb1 : bb0;
    unsigned short* xnb = s ? xnb1 : xnb0;
    int tl = t & 63, tg = t >> 6;
#pragma unroll
    for (int i = 0; i < 16; i++) {
        int cl = tg * 16 + i;
        tile[cl][tl] = x[((size_t)(b * CDIM + c0 + cl)) * LDIM + l0 + tl];
    }
    __syncthreads();
    const size_t SZ = (size_t)BDIM * LDIM * CDIM;
#pragma unroll
    for (int i = 0; i < 16; i++) {
        int ll = tg * 16 + i;
        int l = l0 + ll, c = c0 + tl;
        float v = tile[tl][ll];
        int sidx = s * 8192 + b * LDIM + l;
        float m = stats[sidx * 2], rs = stats[sidx * 2 + 1];
        size_t o = ((size_t)(b * LDIM + l)) * CDIM + c;
        out[(size_t)s * SZ + o] = v;  // residual pre-store
        xnb[o] = f2bf((v - m) * rs * g[c] + bb[c]);
    }
}

// ---------- weight transpose/convert: W (K,N) fp32 -> Wt (N,K) bf16 ----------
__global__ __launch_bounds__(256) void wt_transpose(const float* __restrict__ W,
                                                    unsigned short* __restrict__ Wt,
                                                    int K, int N)
{
    __shared__ float tile[64][65];
    int t = threadIdx.x;
    int n0 = blockIdx.x * 64, k0 = blockIdx.y * 64;
    int tn = t & 63, tg = t >> 6;
#pragma unroll
    for (int i = 0; i < 16; i++) {
        int kl = tg * 16 + i;
        tile[kl][tn] = W[(size_t)(k0 + kl) * N + n0 + tn];
    }
    __syncthreads();
#pragma unroll
    for (int i = 0; i < 16; i++) {
        int nl = tg * 16 + i;
        int k = k0 + tn, n = n0 + nl;
        Wt[(size_t)n * K + k] = f2bf(tile[tn][nl]);
    }
}

// ---------- Wcomb = Wxp[:, :48] @ Wdt  -> WcombT (N=768, K=768) bf16 ----------
__global__ __launch_bounds__(256) void wcomb_kernel(const float* __restrict__ Wxp,
                                                    const float* __restrict__ Wdt,
                                                    unsigned short* __restrict__ WcombT)
{
    int t = threadIdx.x;
    int k = blockIdx.x * 64 + (t & 63);
    int n0 = blockIdx.y * 64;
    float wx[RNK];
#pragma unroll
    for (int r = 0; r < RNK; r++) wx[r] = Wxp[k * 56 + r];
    for (int i = (t >> 6); i < 64; i += 4) {
        int n = n0 + i;
        float acc = 0.f;
#pragma unroll
        for (int r = 0; r < RNK; r++) acc += wx[r] * Wdt[(size_t)r * CDIM + n];
        WcombT[(size_t)n * CDIM + k] = f2bf(acc);
    }
}

// ---------- bf16 MFMA GEMM, 2 streams via blockIdx.z, XOR-swizzled LDS ----------
// 3-stage software pipeline: tiles i+1, i+2 in flight while computing tile i.
// Raw s_barrier + partial s_waitcnt vmcnt(N) (never 0 until the tail) so prefetch
// loads stay in flight across the barrier (the __syncthreads vmcnt(0) drain was
// the structural stall: MfmaUtil 10%, VALUBusy 16%, both pipes idle).
// Grid: x = ROW tile, y = COL tile (same-row blocks -> same XCD -> A L2 reuse).
// epi 1: fp32 C += acc (residual pre-stored); epi 2: bf16 softplus(acc+bias); epi 3: bf16 store
__global__ __launch_bounds__(256) void gemm_mfma(
    const unsigned short* __restrict__ A0, const unsigned short* __restrict__ A1,
    const unsigned short* __restrict__ Bt0, const unsigned short* __restrict__ Bt1,
    void* __restrict__ C0, void* __restrict__ C1, int ldc, int K, int epi,
    const float* __restrict__ bias0, const float* __restrict__ bias1)
{
    const unsigned short* A = blockIdx.z ? A1 : A0;
    const unsigned short* Bt = blockIdx.z ? Bt1 : Bt0;
    void* C = blockIdx.z ? C1 : C0;
    const float* bias = blockIdx.z ? bias1 : bias0;

    __shared__ unsigned short As[3][128 * 32];
    __shared__ unsigned short Bs[3][128 * 32];
    const int tid = threadIdx.x;
    const int wave = tid >> 6, lane = tid & 63;
    const int row0 = blockIdx.x * 128, col0 = blockIdx.y * 128;
    const int wm = (wave >> 1) * 64, wn = (wave & 1) * 64;
    f32x4 acc[4][4] = {};
    const int lr = lane >> 2;                                // staging row within 16
    const int gi = ((lane & 3) ^ ((lane >> 3) & 3)) * 8;     // swizzled global k-chunk
    const int fr = lane & 15, fc = lane >> 4;                // fragment row / k-chunk

    const unsigned short* ga0 = A + (size_t)(row0 + wave * 32 + lr) * K + gi;
    const unsigned short* gb0 = Bt + (size_t)(col0 + wave * 32 + lr) * K + gi;
    const int rb = wave * 32;

#define ISSUE(st, kb)                                              \
    do {                                                           \
        llds16(ga0 + (kb), &As[st][rb * 32]);                      \
        llds16(gb0 + (kb), &Bs[st][rb * 32]);                      \
        llds16(ga0 + (size_t)16 * K + (kb), &As[st][(rb + 16) * 32]); \
        llds16(gb0 + (size_t)16 * K + (kb), &Bs[st][(rb + 16) * 32]); \
    } while (0)

    const int NIT = K / 32;
    ISSUE(0, 0);
    ISSUE(1, 32);
    for (int i = 0; i < NIT; i++) {
        int rem = NIT - 1 - i;
        if (rem >= 2) __builtin_amdgcn_s_waitcnt(0xF78);       // vmcnt(8): tile i landed
        else if (rem == 1) __builtin_amdgcn_s_waitcnt(0xF74);  // vmcnt(4)
        else __builtin_amdgcn_s_waitcnt(0xF70);                // vmcnt(0)
        __builtin_amdgcn_s_barrier();
        if (i + 2 < NIT) {
            int st = (i + 2) % 3;
            int kb = (i + 2) * 32;
            ISSUE(st, kb);
        }
        const unsigned short* as = As[i % 3];
        const unsigned short* bs = Bs[i % 3];
        bf16x8 af[4], bfr[4];
#pragma unroll
        for (int ii = 0; ii < 4; ii++) {
            int r = wm + ii * 16 + fr;
            af[ii] = *(const bf16x8*)&as[r * 32 + (fc ^ ((r >> 1) & 3)) * 8];
        }
#pragma unroll
        for (int j = 0; j < 4; j++) {
            int r = wn + j * 16 + fr;
            bfr[j] = *(const bf16x8*)&bs[r * 32 + (fc ^ ((r >> 1) & 3)) * 8];
        }
#pragma unroll
        for (int ii = 0; ii < 4; ii++)
#pragma unroll
            for (int j = 0; j < 4; j++)
                acc[ii][j] = __builtin_amdgcn_mfma_f32_16x16x32_bf16(af[ii], bfr[j], acc[ii][j], 0, 0, 0);
    }
#undef ISSUE

    const int cr = (lane >> 4) * 4, cc = lane & 15;
#pragma unroll
    for (int i = 0; i < 4; i++)
#pragma unroll
        for (int j = 0; j < 4; j++) {
            int col = col0 + wn + j * 16 + cc;
#pragma unroll
            for (int r = 0; r < 4; r++) {
                int row = row0 + wm + i * 16 + cr + r;
                size_t o = (size_t)row * ldc + col;
                float v = acc[i][j][r];
                if (epi == 1) {
                    float* Cf = (float*)C;
                    Cf[o] = v + Cf[o];
                } else if (epi == 2) {
                    v += bias[col];
                    v = (v > 20.f) ? v : __logf(1.f + __expf(v));
                    ((unsigned short*)C)[o] = f2bf(v);
                } else {
                    ((unsigned short*)C)[o] = f2bf(v);
                }
            }
        }
}

// ---------- depthwise causal conv (K=4) + SiLU; vectorized: 8 d's/thread, taps as bf16x8 loads ----------
__global__ __launch_bounds__(256) void conv_silu_kernel(
    const unsigned short* __restrict__ uzb0, const unsigned short* __restrict__ uzb1,
    const float* __restrict__ w0, const float* __restrict__ bc0,
    const float* __restrict__ w1, const float* __restrict__ bc1,
    unsigned short* __restrict__ ub0, unsigned short* __restrict__ ub1)
{
    int s = blockIdx.y;
    const unsigned short* uzb = s ? uzb1 : uzb0;
    const float* w = s ? w1 : w0;
    const float* bc = s ? bc1 : bc0;
    unsigned short* ub = s ? ub1 : ub0;
    int idx = blockIdx.x * 256 + threadIdx.x;  // over M*CDIM/8
    int d8 = (idx % 96) * 8;
    int bl = idx / 96;
    int l = bl & (LDIM - 1);

    float wr[8][4];
#pragma unroll
    for (int q = 0; q < 8; q++) {
        f32x4 wv = *(const f32x4*)&w[(d8 + q) * 4];
#pragma unroll
        for (int k = 0; k < 4; k++) wr[q][k] = wv[k];
    }
    float acc[8];
    f32x4 b0 = *(const f32x4*)&bc[d8];
    f32x4 b1 = *(const f32x4*)&bc[d8 + 4];
#pragma unroll
    for (int q = 0; q < 4; q++) { acc[q] = b0[q]; acc[4 + q] = b1[q]; }

#pragma unroll
    for (int k = 0; k < 4; k++) {
        int ls = l - 3 + k;
        if (ls >= 0) {
            bf16x8 uv = *(const bf16x8*)&uzb[(size_t)(bl - 3 + k) * (2 * CDIM) + d8];
#pragma unroll
            for (int q = 0; q < 8; q++)
                acc[q] += bf2f((unsigned short)uv[q]) * wr[q][k];
        }
    }
    bf16x8 ov;
#pragma unroll
    for (int q = 0; q < 8; q++) {
        float v = acc[q];
        ov[q] = (short)f2bf(v * sigmoidf_(v));
    }
    *(bf16x8*)&ub[(size_t)bl * CDIM + d8] = ov;
}

// ---------- B/C projection GEMV: dbl(M,8) = u @ Wxp[:, 48:56] ----------
__global__ __launch_bounds__(256) void bc_gemv(
    const unsigned short* __restrict__ ub0, const unsigned short* __restrict__ ub1,
    const float* __restrict__ Wxp0, const float* __restrict__ Wxp1,
    float* __restrict__ dbl0, float* __restrict__ dbl1)
{
    int s = blockIdx.y;
    const unsigned short* ub = s ? ub1 : ub0;
    const float* Wxp = s ? Wxp1 : Wxp0;
    float* dbl = s ? dbl1 : dbl0;
    __shared__ float Wl[CDIM][8];
    int t = threadIdx.x;
    for (int i = t; i < CDIM * 8; i += 256) {
        int k = i >> 3, c = i & 7;
        Wl[k][c] = Wxp[k * 56 + RNK + c];
    }
    __syncthreads();
    int c = t & 7;
    int row = blockIdx.x * 32 + (t >> 3);
    const unsigned short* up = ub + (size_t)row * CDIM;
    float acc = 0.f;
    for (int k = 0; k < CDIM; k += 8) {
        bf16x8 uv = *(const bf16x8*)&up[k];
#pragma unroll
        for (int j = 0; j < 8; j++)
            acc += bf2f((unsigned short)uv[j]) * Wl[k + j][c];
    }
    dbl[(size_t)row * 8 + c] = acc;
}

// ---------- chunked selective scan; u/dt/z all bf16 ----------
__global__ __launch_bounds__(256) void scan_phaseA(
    const unsigned short* __restrict__ u0, const unsigned short* __restrict__ dt0,
    const float* __restrict__ dbl0, const float* __restrict__ Alog0,
    const unsigned short* __restrict__ u1, const unsigned short* __restrict__ dt1,
    const float* __restrict__ dbl1, const float* __restrict__ Alog1,
    float* __restrict__ agg)
{
    int idx = blockIdx.x * 256 + threadIdx.x;
    int d = idx % CDIM;
    int t1 = idx / CDIM;
    int c = t1 % CH;
    int t2 = t1 / CH;
    int b = t2 & 1;
    int s = t2 >> 1;
    const unsigned short* u = s ? u1 : u0;
    const unsigned short* dt = s ? dt1 : dt0;
    const float* dbl = s ? dbl1 : dbl0;
    const float* Alog = s ? Alog1 : Alog0;
    float A[4];
#pragma unroll
    for (int n = 0; n < 4; n++) A[n] = -__expf(Alog[d * 4 + n]);
    float h[4] = {0, 0, 0, 0}, aa[4] = {1, 1, 1, 1};
    int rowb = b * LDIM + c * LC;
    for (int t = 0; t < LC; t++) {
        int row = rowb + t;
        float dtv = bf2f(dt[(size_t)row * CDIM + d]);
        float uv = bf2f(u[(size_t)row * CDIM + d]);
        float du = dtv * uv;
        const float* bm = dbl + (size_t)row * 8;
#pragma unroll
        for (int n = 0; n < 4; n++) {
            float dA = __expf(dtv * A[n]);
            h[n] = dA * h[n] + du * bm[n];
            aa[n] *= dA;
        }
    }
    float* o = agg + (size_t)idx * 8;
#pragma unroll
    for (int n = 0; n < 4; n++) { o[n] = aa[n]; o[4 + n] = h[n]; }
}

__global__ __launch_bounds__(256) void scan_phaseB(const float* __restrict__ agg,
                                                   float* __restrict__ hinit)
{
    int idx = blockIdx.x * 256 + threadIdx.x;
    int d = idx % CDIM;
    int sb = idx / CDIM;
    float st[4] = {0, 0, 0, 0};
    for (int c = 0; c < CH; c++) {
        size_t base = ((size_t)sb * CH + c) * CDIM + d;
        const float* a = agg + base * 8;
        float* hi = hinit + base * 4;
#pragma unroll
        for (int n = 0; n < 4; n++) hi[n] = st[n];
#pragma unroll
        for (int n = 0; n < 4; n++) st[n] = a[n] * st[n] + a[4 + n];
    }
}

__global__ __launch_bounds__(256) void scan_phaseC(
    const unsigned short* __restrict__ u0, const unsigned short* __restrict__ dt0,
    const unsigned short* __restrict__ uzb0, const float* __restrict__ dbl0,
    const float* __restrict__ Alog0, const float* __restrict__ Dsk0, unsigned short* __restrict__ g0,
    const unsigned short* __restrict__ u1, const unsigned short* __restrict__ dt1,
    const unsigned short* __restrict__ uzb1, const float* __restrict__ dbl1,
    const float* __restrict__ Alog1, const float* __restrict__ Dsk1, unsigned short* __restrict__ g1,
    const float* __restrict__ hinit)
{
    int idx = blockIdx.x * 256 + threadIdx.x;
    int d = idx % CDIM;
    int t1 = idx / CDIM;
    int c = t1 % CH;
    int t2 = t1 / CH;
    int b = t2 & 1;
    int s = t2 >> 1;
    const unsigned short* u = s ? u1 : u0;
    const unsigned short* dt = s ? dt1 : dt0;
    const unsigned short* uzb = s ? uzb1 : uzb0;
    const float* dbl = s ? dbl1 : dbl0;
    const float* dblO = s ? dbl0 : dbl1;  // cross: other stream's C projection
    const float* Alog = s ? Alog1 : Alog0;
    const float* Dsk = s ? Dsk1 : Dsk0;
    unsigned short* gated = s ? g1 : g0;
    float A[4];
#pragma unroll
    for (int n = 0; n < 4; n++) A[n] = -__expf(Alog[d * 4 + n]);
    float Dv = Dsk[d];
    float h[4];
    const float* hi = hinit + (size_t)idx * 4;
#pragma unroll
    for (int n = 0; n < 4; n++) h[n] = hi[n];
    int rowb = b * LDIM + c * LC;
    for (int t = 0; t < LC; t++) {
        int row = rowb + t;
        float dtv = bf2f(dt[(size_t)row * CDIM + d]);
        float uv = bf2f(u[(size_t)row * CDIM + d]);
        float du = dtv * uv;
        const float* bm = dbl + (size_t)row * 8;
        const float* cm = dblO + (size_t)row * 8 + 4;
        float y = 0.f;
#pragma unroll
        for (int n = 0; n < 4; n++) {
            float dA = __expf(dtv * A[n]);
            h[n] = dA * h[n] + du * bm[n];
            y += h[n] * cm[n];
        }
        y += uv * Dv;
        float zv = bf2f(uzb[(size_t)row * (2 * CDIM) + CDIM + d]);
        gated[(size_t)row * CDIM + d] = f2bf(y * (zv * sigmoidf_(zv)));
    }
}

extern "C" void kernel_launch(void* const* d_in, const int* in_sizes, int n_in,
                              void* d_out, int out_size, void* d_ws, size_t ws_size,
                              hipStream_t stream)
{
    const float* x[2] = {(const float*)d_in[0], (const float*)d_in[1]};
    const float *ln_g[2], *ln_b[2], *Win[2], *Wconv[2], *bconv[2], *Wxp[2],
        *Wdt[2], *bdt[2], *Alog[2], *Dskip[2], *Wout[2];
    for (int s = 0; s < 2; s++) {
        int base = 2 + s * 11;
        ln_g[s] = (const float*)d_in[base + 0];
        ln_b[s] = (const float*)d_in[base + 1];
        Win[s] = (const float*)d_in[base + 2];
        Wconv[s] = (const float*)d_in[base + 3];
        bconv[s] = (const float*)d_in[base + 4];
        Wxp[s] = (const float*)d_in[base + 5];
        Wdt[s] = (const float*)d_in[base + 6];
        bdt[s] = (const float*)d_in[base + 7];
        Alog[s] = (const float*)d_in[base + 8];
        Dskip[s] = (const float*)d_in[base + 9];
        Wout[s] = (const float*)d_in[base + 10];
    }

    const int M = BDIM * LDIM;  // 8192
    char* base = (char*)d_ws;
    auto alloc = [&](size_t bytes) {
        char* p = base;
        base += (bytes + 255) & ~(size_t)255;
        return p;
    };
    unsigned short* uzb[2] = {(unsigned short*)alloc((size_t)M * 1536 * 2),
                              (unsigned short*)alloc((size_t)M * 1536 * 2)};
    unsigned short* dtb[2] = {(unsigned short*)alloc((size_t)M * CDIM * 2),
                              (unsigned short*)alloc((size_t)M * CDIM * 2)};
    unsigned short* ub[2] = {(unsigned short*)alloc((size_t)M * CDIM * 2),
                             (unsigned short*)alloc((size_t)M * CDIM * 2)};
    unsigned short* xnb[2] = {(unsigned short*)alloc((size_t)M * CDIM * 2),
                              (unsigned short*)alloc((size_t)M * CDIM * 2)};  // reused as gated
    float* dbl[2] = {(float*)alloc((size_t)M * 8 * 4), (float*)alloc((size_t)M * 8 * 4)};
    unsigned short* WinT[2] = {(unsigned short*)alloc(1536 * 768 * 2),
                               (unsigned short*)alloc(1536 * 768 * 2)};
    unsigned short* WoutT[2] = {(unsigned short*)alloc(768 * 768 * 2),
                                (unsigned short*)alloc(768 * 768 * 2)};
    unsigned short* WcombT[2] = {(unsigned short*)alloc(768 * 768 * 2),
                                 (unsigned short*)alloc(768 * 768 * 2)};
    float* agg = (float*)alloc((size_t)2 * BDIM * CH * CDIM * 8 * 4);
    float* hinit = (float*)alloc((size_t)2 * BDIM * CH * CDIM * 4 * 4);
    float* stats = (float*)alloc((size_t)2 * M * 2 * 4);

    dim3 blk(256);
    const size_t SZ = (size_t)BDIM * LDIM * CDIM;

    // LN stats + transpose (pre-stores residual into d_out)
    stats_kernel<<<dim3(256), blk, 0, stream>>>(x[0], x[1], stats);
    transpose_ln_kernel<<<dim3(CDIM / 64, LDIM / 64, 4), blk, 0, stream>>>(
        x[0], x[1], ln_g[0], ln_b[0], ln_g[1], ln_b[1], stats, xnb[0], xnb[1], (float*)d_out);

    // weight prep
    for (int s = 0; s < 2; s++) {
        wt_transpose<<<dim3(1536 / 64, 768 / 64), blk, 0, stream>>>(Win[s], WinT[s], CDIM, 2 * CDIM);
        wt_transpose<<<dim3(768 / 64, 768 / 64), blk, 0, stream>>>(Wout[s], WoutT[s], CDIM, CDIM);
        wcomb_kernel<<<dim3(768 / 64, 768 / 64), blk, 0, stream>>>(Wxp[s], Wdt[s], WcombT[s]);
    }

    // in_proj (both streams): bf16 MFMA -> uzb bf16 (M,1536); grid x=row-tile for XCD L2 reuse
    gemm_mfma<<<dim3(M / 128, 1536 / 128, 2), blk, 0, stream>>>(
        xnb[0], xnb[1], WinT[0], WinT[1], uzb[0], uzb[1], 2 * CDIM, CDIM, 3, nullptr, nullptr);

    // depthwise conv + SiLU (both streams) -> ub bf16
    conv_silu_kernel<<<dim3((M * CDIM / 8) / 256, 2), blk, 0, stream>>>(
        uzb[0], uzb[1], Wconv[0], bconv[0], Wconv[1], bconv[1], ub[0], ub[1]);

    // dt = softplus(u @ Wcomb + bdt) -> dtb bf16 (both streams)
    gemm_mfma<<<dim3(M / 128, CDIM / 128, 2), blk, 0, stream>>>(
        ub[0], ub[1], WcombT[0], WcombT[1], dtb[0], dtb[1], CDIM, CDIM, 2, bdt[0], bdt[1]);

    // B/C projection for both streams
    bc_gemv<<<dim3(M / 32, 2), blk, 0, stream>>>(ub[0], ub[1], Wxp[0], Wxp[1], dbl[0], dbl[1]);

    // cross selective scan (3 phases); gating fused, writes bf16 gated into xnb
    scan_phaseA<<<dim3((2 * BDIM * CH * CDIM) / 256), blk, 0, stream>>>(
        ub[0], dtb[0], dbl[0], Alog[0], ub[1], dtb[1], dbl[1], Alog[1], agg);
    scan_phaseB<<<dim3((2 * BDIM * CDIM) / 256), blk, 0, stream>>>(agg, hinit);
    scan_phaseC<<<dim3((2 * BDIM * CH * CDIM) / 256), blk, 0, stream>>>(
        ub[0], dtb[0], uzb[0], dbl[0], Alog[0], Dskip[0], xnb[0],
        ub[1], dtb[1], uzb[1], dbl[1], Alog[1], Dskip[1], xnb[1], hinit);

    // out_proj (both streams): bf16 MFMA, adds into pre-stored residual in d_out
    float* out = (float*)d_out;
    gemm_mfma<<<dim3(M / 128, CDIM / 128, 2), blk, 0, stream>>>(
        xnb[0], xnb[1], WoutT[0], WoutT[1], out, out + SZ, CDIM, CDIM, 1, nullptr, nullptr);
}